// Round 6
// baseline (5009.071 us; speedup 1.0000x reference)
//
#include <hip/hip_runtime.h>

#define BB 8
#define CC 512
#define NN 4096
#define GG 32
#define OQKV 1536
#define EPSV 1e-5f
#define SCALE 0.044194173824159216f  // 1/sqrt(512)

// per-batch u16 offsets inside the qkv workspace region: [v | q | k]
#define BATCH_STRIDE 6291456u   // 1536*4096
#define V_OFF 0u
#define Q_OFF 2097152u          // 512*4096
#define K_OFF 4194304u

typedef unsigned short u16;
typedef unsigned int u32;
typedef __attribute__((ext_vector_type(8))) short bf16x8;
typedef __attribute__((ext_vector_type(4))) float f32x4;

#define FOR16(OP) OP(0) OP(1) OP(2) OP(3) OP(4) OP(5) OP(6) OP(7) \
                  OP(8) OP(9) OP(10) OP(11) OP(12) OP(13) OP(14) OP(15)
#define FOR32(OP) FOR16(OP) OP(16) OP(17) OP(18) OP(19) OP(20) OP(21) OP(22) OP(23) \
                  OP(24) OP(25) OP(26) OP(27) OP(28) OP(29) OP(30) OP(31)

__device__ __forceinline__ u16 f2bf(float f) {
  u32 u = __float_as_uint(f);
  u32 r = (u + 0x7FFFu + ((u >> 16) & 1u)) >> 16;  // RNE
  return (u16)r;
}

__device__ __forceinline__ u32 pack2bf(float a, float b) {
  return (u32)f2bf(a) | ((u32)f2bf(b) << 16);
}

__device__ __forceinline__ void gload_lds16(const u16* g, u16* l) {
  __builtin_amdgcn_global_load_lds(
      (const __attribute__((address_space(1))) u32*)(g),
      (__attribute__((address_space(3))) u32*)(l), 16, 0, 0);
}

// ---------------- GroupNorm statistics: one block per (b, group) ----------------
__global__ __launch_bounds__(256) void gn_stats_kernel(const float* __restrict__ x,
                                                       float* __restrict__ stats) {
  const int bg = blockIdx.x;
  const float4* xp = (const float4*)(x + (size_t)bg * 16 * NN);
  const int n4 = 16 * NN / 4;
  float s = 0.f, ss = 0.f;
  for (int i = threadIdx.x; i < n4; i += 256) {
    float4 v = xp[i];
    s += v.x + v.y + v.z + v.w;
    ss += v.x * v.x + v.y * v.y + v.z * v.z + v.w * v.w;
  }
  for (int off = 32; off > 0; off >>= 1) {
    s += __shfl_down(s, off, 64);
    ss += __shfl_down(ss, off, 64);
  }
  __shared__ float rs[4], rss[4];
  const int wid = threadIdx.x >> 6, lane = threadIdx.x & 63;
  if (lane == 0) { rs[wid] = s; rss[wid] = ss; }
  __syncthreads();
  if (threadIdx.x == 0) {
    float S = rs[0] + rs[1] + rs[2] + rs[3];
    float SS = rss[0] + rss[1] + rss[2] + rss[3];
    const float invn = 1.0f / (16.0f * NN);
    float mean = S * invn;
    float var = SS * invn - mean * mean;
    stats[bg * 2] = mean;
    stats[bg * 2 + 1] = rsqrtf(var + EPSV);
  }
}

// ------------- GN-apply + transpose: x [C][N] fp32 -> hT [N][C] bf16 -------------
__global__ __launch_bounds__(256) void gn_transpose_kernel(
    const float* __restrict__ x, const float* __restrict__ gamma,
    const float* __restrict__ beta, const float* __restrict__ stats,
    u16* __restrict__ hT) {
  __shared__ __align__(16) u16 Ts[64 * 64];  // XOR-swizzled 16B units
  const int b = blockIdx.z;
  const int c0 = blockIdx.y * 64;
  const int n0 = blockIdx.x * 64;
  const int t = threadIdx.x;
  const float* xb = x + ((size_t)b * CC + c0) * NN;
#pragma unroll
  for (int it = 0; it < 2; ++it) {
    const int U = it * 256 + t;
    const int r = U >> 3, cu = U & 7;  // r = channel row, cu = 8-elem n unit
    const int c = c0 + r;
    const int g = c >> 4;
    const float mean = stats[(b * GG + g) * 2];
    const float rstd = stats[(b * GG + g) * 2 + 1];
    const float aa = rstd * gamma[c];
    const float dd = beta[c] - mean * aa;
    const float* src = xb + (size_t)r * NN + n0 + cu * 8;
    float4 v0 = *(const float4*)src;
    float4 v1 = *(const float4*)(src + 4);
    uint4 pk;
    pk.x = pack2bf(fmaf(aa, v0.x, dd), fmaf(aa, v0.y, dd));
    pk.y = pack2bf(fmaf(aa, v0.z, dd), fmaf(aa, v0.w, dd));
    pk.z = pack2bf(fmaf(aa, v1.x, dd), fmaf(aa, v1.y, dd));
    pk.w = pack2bf(fmaf(aa, v1.z, dd), fmaf(aa, v1.w, dd));
    const int pu = cu ^ ((r >> 3) & 7);
    *(uint4*)((char*)Ts + r * 128 + pu * 16) = pk;
  }
  __syncthreads();
#pragma unroll
  for (int it = 0; it < 2; ++it) {
    const int U = it * 256 + t;
    const int n = U >> 3, cu2 = U & 7;
    bf16x8 v;
#pragma unroll
    for (int jj = 0; jj < 8; ++jj) {
      const int c = cu2 * 8 + jj;
      v[jj] = (short)Ts[c * 64 + (((n >> 3) ^ cu2) << 3) + (n & 7)];
    }
    *(bf16x8*)(hT + ((size_t)b * NN + n0 + n) * CC + c0 + cu2 * 8) = v;
  }
}

// ------------- w_qkv fp32 -> bf16 (one-shot, tiny) -------------
__global__ __launch_bounds__(256) void convert_w_kernel(const float* __restrict__ w,
                                                        u16* __restrict__ wb, int n8) {
  const int i = blockIdx.x * 256 + threadIdx.x;
  if (i >= n8) return;
  const float4 a = *(const float4*)(w + (size_t)i * 8);
  const float4 b = *(const float4*)(w + (size_t)i * 8 + 4);
  uint4 pk;
  pk.x = pack2bf(a.x, a.y);
  pk.y = pack2bf(a.z, a.w);
  pk.z = pack2bf(b.x, b.y);
  pk.w = pack2bf(b.z, b.w);
  *(uint4*)(wb + (size_t)i * 8) = pk;
}

// ------------- QKV GEMM on MFMA: qkv[o][n] = wbf[o][c] * hT[n][c]^T + bias -------------
__global__ __launch_bounds__(256) void qkv_mfma_kernel(
    const u16* __restrict__ hT, const u16* __restrict__ wbf,
    const float* __restrict__ bqkv, u16* __restrict__ qkv) {
  __shared__ __align__(16) u16 Asb[128 * 32 * 2];  // A tile | B tile, 16 KB
  u16* const Bsb = Asb + 128 * 32;
  const int b = blockIdx.z;
  const int o0 = blockIdx.y * 128;
  const int n0 = blockIdx.x * 128;
  const int t = threadIdx.x;
  const int w = t >> 6;
  const int lane = t & 63;
  const int quad = lane >> 4;
  const int m16 = lane & 15;
  const int wm = w >> 1, wn = w & 1;

  const int sr = lane >> 2;
  const int gu = (lane & 3) ^ ((lane >> 3) & 3);
  const u16* gA0 = wbf + (size_t)(o0 + w * 32 + sr) * CC + gu * 8;
  const u16* gA1 = gA0 + (size_t)16 * CC;
  const u16* hTb = hT + (size_t)b * NN * CC;
  const u16* gB0 = hTb + (size_t)(n0 + w * 32 + sr) * CC + gu * 8;
  const u16* gB1 = gB0 + (size_t)16 * CC;
  u16* const lA0 = Asb + (w * 32) * 32;
  u16* const lA1 = Asb + (w * 32 + 16) * 32;
  u16* const lB0 = Bsb + (w * 32) * 32;
  u16* const lB1 = Bsb + (w * 32 + 16) * 32;

  const int sfr = (m16 >> 1) & 3;
  const u16* aP[4];
  const u16* bP[4];
#pragma unroll
  for (int mt = 0; mt < 4; ++mt)
    aP[mt] = Asb + (wm * 64 + mt * 16 + m16) * 32 + (quad ^ sfr) * 8;
#pragma unroll
  for (int ct = 0; ct < 4; ++ct)
    bP[ct] = Bsb + (wn * 64 + ct * 16 + m16) * 32 + (quad ^ sfr) * 8;

  f32x4 acc[4][4];
#pragma unroll
  for (int mt = 0; mt < 4; ++mt)
#pragma unroll
    for (int ct = 0; ct < 4; ++ct) acc[mt][ct] = (f32x4){0.f, 0.f, 0.f, 0.f};

  for (int kk = 0; kk < 16; ++kk) {
    __syncthreads();
    gload_lds16(gA0, lA0);
    gload_lds16(gA1, lA1);
    gload_lds16(gB0, lB0);
    gload_lds16(gB1, lB1);
    gA0 += 32; gA1 += 32; gB0 += 32; gB1 += 32;
    __syncthreads();
    bf16x8 af[4], bfr[4];
#pragma unroll
    for (int mt = 0; mt < 4; ++mt) af[mt] = *(const bf16x8*)aP[mt];
#pragma unroll
    for (int ct = 0; ct < 4; ++ct) bfr[ct] = *(const bf16x8*)bP[ct];
#pragma unroll
    for (int mt = 0; mt < 4; ++mt)
#pragma unroll
      for (int ct = 0; ct < 4; ++ct)
        acc[mt][ct] = __builtin_amdgcn_mfma_f32_16x16x32_bf16(af[mt], bfr[ct],
                                                              acc[mt][ct], 0, 0, 0);
  }
  __syncthreads();

  u16* qb = qkv + (size_t)b * BATCH_STRIDE;
  size_t roff;
  int lo0;
  if (o0 < 512) { roff = Q_OFF; lo0 = o0; }
  else if (o0 < 1024) { roff = K_OFF; lo0 = o0 - 512; }
  else { roff = V_OFF; lo0 = o0 - 1024; }

  u16* const scr = Asb + w * 1024;
#pragma unroll
  for (int mt = 0; mt < 4; ++mt) {
#pragma unroll
    for (int ct = 0; ct < 4; ++ct) {
#pragma unroll
      for (int i = 0; i < 4; ++i) {
        const int row = quad * 4 + i;
        const int nn = ct * 16 + m16;
        const int pu = (nn >> 3) ^ ((row & 7) ^ (row >> 3));
        scr[row * 64 + pu * 8 + (nn & 7)] =
            f2bf(acc[mt][ct][i] + bqkv[o0 + wm * 64 + mt * 16 + row]);
      }
    }
    __syncthreads();
#pragma unroll
    for (int half = 0; half < 2; ++half) {
      const int idx = half * 64 + lane;
      const int row = idx >> 3;
      const int cu = idx & 7;
      const int pu = cu ^ ((row & 7) ^ (row >> 3));
      bf16x8 vv = *(const bf16x8*)(scr + row * 64 + pu * 8);
      *(bf16x8*)(qb + roff + (size_t)(lo0 + wm * 64 + mt * 16 + row) * NN +
                 n0 + wn * 64 + cu * 8) = vv;
    }
    __syncthreads();
  }
}

// ------------- 64x64 tile transpose q,k: [c][n] -> [n][c] bf16 -------------
__global__ __launch_bounds__(256) void transpose_qk_kernel(
    const u16* __restrict__ qkvbuf, u16* __restrict__ qT, u16* __restrict__ kT) {
  __shared__ __align__(16) u16 Ts[64 * 64];  // XOR-swizzled 16B units
  const int b = blockIdx.z >> 1;
  const int which = blockIdx.z & 1;
  const int c0 = blockIdx.y * 64;
  const int n0 = blockIdx.x * 64;
  const int t = threadIdx.x;
  const u16* src = qkvbuf + (size_t)b * BATCH_STRIDE + (which ? K_OFF : Q_OFF);
  u16* dst = (which ? kT : qT) + (size_t)b * (CC * NN);
#pragma unroll
  for (int it = 0; it < 2; ++it) {
    const int U = it * 256 + t;
    const int r = U >> 3, cu = U & 7;
    const int pu = cu ^ ((r >> 3) & 7);
    *(uint4*)((char*)Ts + r * 128 + pu * 16) =
        *(const uint4*)(src + (size_t)(c0 + r) * NN + n0 + cu * 8);
  }
  __syncthreads();
#pragma unroll
  for (int it = 0; it < 2; ++it) {
    const int U = it * 256 + t;
    const int n = U >> 3, cu2 = U & 7;
    bf16x8 v;
#pragma unroll
    for (int jj = 0; jj < 8; ++jj) {
      const int c = cu2 * 8 + jj;
      v[jj] = (short)Ts[c * 64 + (((n >> 3) ^ cu2) << 3) + (n & 7)];
    }
    *(bf16x8*)(dst + (size_t)(n0 + n) * CC + c0 + cu2 * 8) = v;
  }
}

// ------------- Flash attention, wave-local softmax (swapped QK^T), 1 barrier/iter ----
// 8 waves x 512 threads; wave w owns 16 q-rows, ALL 512 channels.
// O accumulators FORCED into AGPRs via inline-asm MFMA "+a" constraints: the
// allocator pins arch VGPRs at 128 (R4/R5 evidence: identical counters across
// launch_bounds variants) and spilled ~12 f32x4 accs/iter = 3.1 GB/dispatch of
// scratch writes. AGPRs sidestep the arch-VGPR cap; waves_per_eu(2) also asks
// for the 256-reg budget directly (LDS already limits to 1 block/CU).
__global__ __attribute__((amdgpu_flat_work_group_size(512, 512),
                          amdgpu_waves_per_eu(2))) void attn_mfma_kernel(
    u16* __restrict__ qkvbuf, const u16* __restrict__ qT, const u16* __restrict__ kT) {
  // Kt dbuf 2x32KB | Vt dbuf 2x32KB | Pb 8 x [16][40] u16
  __shared__ __align__(16) u16 smem[70656];
  u16* const KtA = smem;             // 16384 u16 each
  u16* const KtB = smem + 16384;
  u16* const VtA = smem + 32768;
  u16* const VtB = smem + 49152;
  u16* const Pbase = smem + 65536;   // 8 * 640 u16

  // XCD-aware: linear dispatch id % 8 selects XCD; bind batch to XCD.
  const int flat = blockIdx.y * 32 + blockIdx.x;   // grid = (32, 8)
  const int b = flat & 7;
  const int i0 = (flat >> 3) * 128;
  const int t = threadIdx.x;
  const int w = t >> 6;
  const int lane = t & 63;
  const int quad = lane >> 4;
  const int m16 = lane & 15;

  const u16* vb = qkvbuf + (size_t)b * BATCH_STRIDE + V_OFF;
  float* obuf = (float*)(qkvbuf + (size_t)b * BATCH_STRIDE + Q_OFF);  // aliases q+k
  const u16* qTb = qT + (size_t)b * (CC * NN);
  const u16* kTb = kT + (size_t)b * (CC * NN);
  u16* const myP = Pbase + w * 640;  // [16][40] wave-private

  const int vsrcu = ((lane & 3) ^ ((lane >> 2) & 3)) * 8;   // V source unit (u16)
  const int vrow = lane >> 2;                                // V row within seg

  // ---- prologue: stage tile 0 into buffer A ----
#pragma unroll
  for (int it = 0; it < 4; ++it) {
    const int j = it * 8 + w;
    gload_lds16(kTb + (size_t)j * CC + (lane ^ (j & 7)) * 8, KtA + j * 512 + lane * 8);
  }
#pragma unroll
  for (int it = 0; it < 4; ++it) {
    const int seg = it * 8 + w;
    const int c = seg * 16 + vrow;
    gload_lds16(vb + (size_t)c * NN + vsrcu, VtA + seg * 512 + lane * 8);
  }

  // Q fragments: 16 named bf16x8 registers (q row = i0 + w*16 + m16)
  const u16* qrow = qTb + (size_t)(i0 + w * 16 + m16) * CC + quad * 8;
#define QDECL(kc) bf16x8 q##kc = *(const bf16x8*)(qrow + kc * 32);
  FOR16(QDECL)
#undef QDECL

  float m_r = -1e30f, l_r = 0.f;  // per q-row (q=m16), replicated across quads
  // O accumulators: 32 named f32x4, forced to AGPRs by the asm "+a" ties below.
#define ODECL(ct) f32x4 o##ct = (f32x4){0.f, 0.f, 0.f, 0.f};
  FOR32(ODECL)
#undef ODECL

  __syncthreads();  // tile 0 staged (vmcnt drained by all waves)

  for (int jt = 0; jt < NN / 32; ++jt) {
    const int cur = jt & 1;
    const u16* Ktc = cur ? KtB : KtA;
    const u16* Vtc = cur ? VtB : VtA;
    // ---- issue next-tile staging into the other buffer (overlaps compute) ----
    if (jt + 1 < NN / 32) {
      u16* Ktn = cur ? KtA : KtB;
      u16* Vtn = cur ? VtA : VtB;
      const int j0n = (jt + 1) * 32;
#pragma unroll
      for (int it = 0; it < 4; ++it) {
        const int j = it * 8 + w;
        gload_lds16(kTb + (size_t)(j0n + j) * CC + (lane ^ (j & 7)) * 8,
                    Ktn + j * 512 + lane * 8);
      }
#pragma unroll
      for (int it = 0; it < 4; ++it) {
        const int seg = it * 8 + w;
        const int c = seg * 16 + vrow;
        gload_lds16(vb + (size_t)c * NN + j0n + vsrcu, Vtn + seg * 512 + lane * 8);
      }
    }
    // ---- S^T = mfma(K, Q): two 16-key tiles, fully static ----
    f32x4 s0 = (f32x4){0.f, 0.f, 0.f, 0.f};
    f32x4 s1 = (f32x4){0.f, 0.f, 0.f, 0.f};
    {
      const u16* k0 = Ktc + m16 * 512;
      const u16* k1 = k0 + 16 * 512;
      const int sz = m16 & 7;
#define SSTEP(kc) { const int u = ((kc * 4 + quad) ^ sz) * 8; \
      bf16x8 ka = *(const bf16x8*)(k0 + u); \
      bf16x8 kb = *(const bf16x8*)(k1 + u); \
      s0 = __builtin_amdgcn_mfma_f32_16x16x32_bf16(ka, q##kc, s0, 0, 0, 0); \
      s1 = __builtin_amdgcn_mfma_f32_16x16x32_bf16(kb, q##kc, s1, 0, 0, 0); }
      FOR16(SSTEP)
#undef SSTEP
    }
    // ---- wave-local online softmax: lane holds 8 scores of q-row m16 ----
    float p0 = s0[0] * SCALE, p1 = s0[1] * SCALE, p2 = s0[2] * SCALE, p3 = s0[3] * SCALE;
    float p4 = s1[0] * SCALE, p5 = s1[1] * SCALE, p6 = s1[2] * SCALE, p7 = s1[3] * SCALE;
    float mx = fmaxf(fmaxf(fmaxf(p0, p1), fmaxf(p2, p3)),
                     fmaxf(fmaxf(p4, p5), fmaxf(p6, p7)));
    mx = fmaxf(mx, __shfl_xor(mx, 16));
    mx = fmaxf(mx, __shfl_xor(mx, 32));
    const float mold = m_r;
    const float mnew = fmaxf(mold, mx);
    m_r = mnew;
    const float alpha = __expf(mold - mnew);
    p0 = __expf(p0 - mnew); p1 = __expf(p1 - mnew);
    p2 = __expf(p2 - mnew); p3 = __expf(p3 - mnew);
    p4 = __expf(p4 - mnew); p5 = __expf(p5 - mnew);
    p6 = __expf(p6 - mnew); p7 = __expf(p7 - mnew);
    float sum = ((p0 + p1) + (p2 + p3)) + ((p4 + p5) + (p6 + p7));
    sum += __shfl_xor(sum, 16);
    sum += __shfl_xor(sum, 32);
    l_r = l_r * alpha + sum;
    // pack P (keys quad*4.., 16+quad*4..) into wave-private Pb[q=m16][key]
    uint2 pw0, pw1;
    pw0.x = pack2bf(p0, p1); pw0.y = pack2bf(p2, p3);
    pw1.x = pack2bf(p4, p5); pw1.y = pack2bf(p6, p7);
    *(uint2*)(myP + m16 * 40 + quad * 4) = pw0;
    *(uint2*)(myP + m16 * 40 + 16 + quad * 4) = pw1;
    asm volatile("s_waitcnt lgkmcnt(0)" ::: "memory");
    // A-frag for PV: P[q=m16][k = quad*8 + j]
    bf16x8 pf = *(const bf16x8*)(myP + m16 * 40 + quad * 8);
    // alpha for this lane's 4 output q-rows (quad*4+r)
    const float a0 = __shfl(alpha, quad * 4 + 0);
    const float a1 = __shfl(alpha, quad * 4 + 1);
    const float a2 = __shfl(alpha, quad * 4 + 2);
    const float a3 = __shfl(alpha, quad * 4 + 3);
    // ---- PV: O[16q][512c], B-frag V[k=key][n=c] from Vt [c][32] swizzled ----
    // Accumulate in AGPRs: asm-tied "+a" keeps o## out of the arch-VGPR budget.
    const u16* vbase = Vtc + m16 * 32 + (quad ^ (m16 & 3)) * 8;
    const bool nores = __all(mnew == mold);
#define PVN(ct) { bf16x8 vf = *(const bf16x8*)(vbase + ct * 512); \
      asm volatile("v_mfma_f32_16x16x32_bf16 %0, %1, %2, %0" \
                   : "+a"(o##ct) : "v"(pf), "v"(vf)); }
#define PVR(ct) { bf16x8 vf = *(const bf16x8*)(vbase + ct * 512); \
      f32x4 oo = o##ct; \
      oo[0] *= a0; oo[1] *= a1; oo[2] *= a2; oo[3] *= a3; \
      o##ct = oo; \
      asm volatile("v_mfma_f32_16x16x32_bf16 %0, %1, %2, %0" \
                   : "+a"(o##ct) : "v"(pf), "v"(vf)); }
    if (nores) {
      FOR32(PVN)
    } else {
      FOR32(PVR)
    }
#undef PVN
#undef PVR
    __syncthreads();  // all waves done with buf[cur]; buf[next] staged & visible
  }
  // ---- epilogue: direct stores; lane's 4 values are contiguous n-positions ----
  const float invl = 1.0f / l_r;
  const float il0 = __shfl(invl, quad * 4 + 0);
  const float il1 = __shfl(invl, quad * 4 + 1);
  const float il2 = __shfl(invl, quad * 4 + 2);
  const float il3 = __shfl(invl, quad * 4 + 3);
  const size_t ncol = i0 + w * 16 + quad * 4;
#define EPI(ct) { float4 ov; \
      ov.x = o##ct[0] * il0; ov.y = o##ct[1] * il1; \
      ov.z = o##ct[2] * il2; ov.w = o##ct[3] * il3; \
      *(float4*)(obuf + (size_t)(ct * 16 + m16) * NN + ncol) = ov; }
  FOR32(EPI)
#undef EPI
}

// ------------- output projection + bias + residual (obuf aliased in qkv ws) -------------
__global__ __launch_bounds__(256) void proj_kernel(
    const u16* __restrict__ qkvbuf, const float* __restrict__ wout,
    const float* __restrict__ bout, const float* __restrict__ x,
    float* __restrict__ out) {
  __shared__ __align__(16) float Wt[16][68];
  __shared__ __align__(16) float Ht[16][68];
  const int b = blockIdx.z;
  const int o0 = blockIdx.y * 64;
  const int n0 = blockIdx.x * 64;
  const int t = threadIdx.x;
  const int to = (t >> 4) * 4;
  const int tn = (t & 15) * 4;
  const int wo = t >> 2;
  const int wk = (t & 3) * 4;
  const int xc = t >> 4;
  const int xn = (t & 15) * 4;
  const float* ob = (const float*)(qkvbuf + (size_t)b * BATCH_STRIDE + Q_OFF);
  float acc[4][4] = {{0.f}};
  for (int kk = 0; kk < CC; kk += 16) {
    float4 wv = *(const float4*)(wout + (size_t)(o0 + wo) * CC + kk + wk);
    float4 hv = *(const float4*)(ob + (size_t)(kk + xc) * NN + n0 + xn);
    __syncthreads();
    Wt[wk + 0][wo] = wv.x;
    Wt[wk + 1][wo] = wv.y;
    Wt[wk + 2][wo] = wv.z;
    Wt[wk + 3][wo] = wv.w;
    *(float4*)&Ht[xc][xn] = hv;
    __syncthreads();
#pragma unroll
    for (int k = 0; k < 16; ++k) {
      float4 w4 = *(const float4*)&Wt[k][to];
      float4 h4 = *(const float4*)&Ht[k][tn];
      acc[0][0] = fmaf(w4.x, h4.x, acc[0][0]);
      acc[0][1] = fmaf(w4.x, h4.y, acc[0][1]);
      acc[0][2] = fmaf(w4.x, h4.z, acc[0][2]);
      acc[0][3] = fmaf(w4.x, h4.w, acc[0][3]);
      acc[1][0] = fmaf(w4.y, h4.x, acc[1][0]);
      acc[1][1] = fmaf(w4.y, h4.y, acc[1][1]);
      acc[1][2] = fmaf(w4.y, h4.z, acc[1][2]);
      acc[1][3] = fmaf(w4.y, h4.w, acc[1][3]);
      acc[2][0] = fmaf(w4.z, h4.x, acc[2][0]);
      acc[2][1] = fmaf(w4.z, h4.y, acc[2][1]);
      acc[2][2] = fmaf(w4.z, h4.z, acc[2][2]);
      acc[2][3] = fmaf(w4.z, h4.w, acc[2][3]);
      acc[3][0] = fmaf(w4.w, h4.x, acc[3][0]);
      acc[3][1] = fmaf(w4.w, h4.y, acc[3][1]);
      acc[3][2] = fmaf(w4.w, h4.z, acc[3][2]);
      acc[3][3] = fmaf(w4.w, h4.w, acc[3][3]);
    }
  }
#pragma unroll
  for (int i = 0; i < 4; ++i) {
    const int o = o0 + to + i;
    const float bias = bout[o];
    const size_t idx = ((size_t)b * CC + o) * NN + n0 + tn;
    float4 xv = *(const float4*)(x + idx);
    float4 r;
    r.x = acc[i][0] + bias + xv.x;
    r.y = acc[i][1] + bias + xv.y;
    r.z = acc[i][2] + bias + xv.z;
    r.w = acc[i][3] + bias + xv.w;
    *(float4*)(out + idx) = r;
  }
}

extern "C" void kernel_launch(void* const* d_in, const int* in_sizes, int n_in,
                              void* d_out, int out_size, void* d_ws, size_t ws_size,
                              hipStream_t stream) {
  const float* x = (const float*)d_in[0];
  const float* gamma = (const float*)d_in[1];
  const float* beta = (const float*)d_in[2];
  const float* wqkv = (const float*)d_in[3];
  const float* bqkv = (const float*)d_in[4];
  const float* wout = (const float*)d_in[5];
  const float* bout = (const float*)d_in[6];
  float* out = (float*)d_out;

  char* ws = (char*)d_ws;
  float* stats = (float*)ws;                           // 2 KB
  u16* qkv = (u16*)(ws + 4096);                        // bf16 [v|q|k] per batch
  u16* qT = (u16*)(ws + 4096 + (size_t)BB * OQKV * NN * 2);      // 33.55 MB
  u16* kT = qT + (size_t)BB * CC * NN;                            // 33.55 MB
  u16* hT = qT;    // alias: [B][N][C] bf16, consumed before transpose_qk writes qT
  u16* wbf = kT;   // alias: [1536][512] bf16

  gn_stats_kernel<<<BB * GG, 256, 0, stream>>>(x, stats);
  gn_transpose_kernel<<<dim3(NN / 64, CC / 64, BB), 256, 0, stream>>>(
      x, gamma, beta, stats, hT);
  convert_w_kernel<<<(OQKV * CC / 8 + 255) / 256, 256, 0, stream>>>(
      wqkv, wbf, OQKV * CC / 8);
  qkv_mfma_kernel<<<dim3(NN / 128, OQKV / 128, BB), 256, 0, stream>>>(
      hT, wbf, bqkv, qkv);
  transpose_qk_kernel<<<dim3(NN / 64, CC / 64, BB * 2), 256, 0, stream>>>(qkv, qT, kT);
  attn_mfma_kernel<<<dim3(NN / 128, BB), 512, 0, stream>>>(qkv, qT, kT);
  proj_kernel<<<dim3(NN / 64, CC / 64, BB), 256, 0, stream>>>(qkv, wout, bout, x, out);
}

// Round 7
// 2464.428 us; speedup vs baseline: 2.0325x; 2.0325x over previous
//
#include <hip/hip_runtime.h>

#define BB 8
#define CC 512
#define NN 4096
#define GG 32
#define OQKV 1536
#define EPSV 1e-5f
#define SCALE 0.044194173824159216f  // 1/sqrt(512)

// per-batch u16 offsets inside the qkv workspace region: [v | q | k]
#define BATCH_STRIDE 6291456u   // 1536*4096
#define V_OFF 0u
#define Q_OFF 2097152u          // 512*4096
#define K_OFF 4194304u

typedef unsigned short u16;
typedef unsigned int u32;
typedef __attribute__((ext_vector_type(8))) short bf16x8;
typedef __attribute__((ext_vector_type(4))) float f32x4;

#define FOR16(OP) OP(0) OP(1) OP(2) OP(3) OP(4) OP(5) OP(6) OP(7) \
                  OP(8) OP(9) OP(10) OP(11) OP(12) OP(13) OP(14) OP(15)
#define FOR32(OP) FOR16(OP) OP(16) OP(17) OP(18) OP(19) OP(20) OP(21) OP(22) OP(23) \
                  OP(24) OP(25) OP(26) OP(27) OP(28) OP(29) OP(30) OP(31)

__device__ __forceinline__ u16 f2bf(float f) {
  u32 u = __float_as_uint(f);
  u32 r = (u + 0x7FFFu + ((u >> 16) & 1u)) >> 16;  // RNE
  return (u16)r;
}

__device__ __forceinline__ u32 pack2bf(float a, float b) {
  return (u32)f2bf(a) | ((u32)f2bf(b) << 16);
}

__device__ __forceinline__ void gload_lds16(const u16* g, u16* l) {
  __builtin_amdgcn_global_load_lds(
      (const __attribute__((address_space(1))) u32*)(g),
      (__attribute__((address_space(3))) u32*)(l), 16, 0, 0);
}

// ---------------- GroupNorm statistics: one block per (b, group) ----------------
__global__ __launch_bounds__(256) void gn_stats_kernel(const float* __restrict__ x,
                                                       float* __restrict__ stats) {
  const int bg = blockIdx.x;
  const float4* xp = (const float4*)(x + (size_t)bg * 16 * NN);
  const int n4 = 16 * NN / 4;
  float s = 0.f, ss = 0.f;
  for (int i = threadIdx.x; i < n4; i += 256) {
    float4 v = xp[i];
    s += v.x + v.y + v.z + v.w;
    ss += v.x * v.x + v.y * v.y + v.z * v.z + v.w * v.w;
  }
  for (int off = 32; off > 0; off >>= 1) {
    s += __shfl_down(s, off, 64);
    ss += __shfl_down(ss, off, 64);
  }
  __shared__ float rs[4], rss[4];
  const int wid = threadIdx.x >> 6, lane = threadIdx.x & 63;
  if (lane == 0) { rs[wid] = s; rss[wid] = ss; }
  __syncthreads();
  if (threadIdx.x == 0) {
    float S = rs[0] + rs[1] + rs[2] + rs[3];
    float SS = rss[0] + rss[1] + rss[2] + rss[3];
    const float invn = 1.0f / (16.0f * NN);
    float mean = S * invn;
    float var = SS * invn - mean * mean;
    stats[bg * 2] = mean;
    stats[bg * 2 + 1] = rsqrtf(var + EPSV);
  }
}

// ------------- GN-apply + transpose: x [C][N] fp32 -> hT [N][C] bf16 -------------
__global__ __launch_bounds__(256) void gn_transpose_kernel(
    const float* __restrict__ x, const float* __restrict__ gamma,
    const float* __restrict__ beta, const float* __restrict__ stats,
    u16* __restrict__ hT) {
  __shared__ __align__(16) u16 Ts[64 * 64];  // XOR-swizzled 16B units
  const int b = blockIdx.z;
  const int c0 = blockIdx.y * 64;
  const int n0 = blockIdx.x * 64;
  const int t = threadIdx.x;
  const float* xb = x + ((size_t)b * CC + c0) * NN;
#pragma unroll
  for (int it = 0; it < 2; ++it) {
    const int U = it * 256 + t;
    const int r = U >> 3, cu = U & 7;  // r = channel row, cu = 8-elem n unit
    const int c = c0 + r;
    const int g = c >> 4;
    const float mean = stats[(b * GG + g) * 2];
    const float rstd = stats[(b * GG + g) * 2 + 1];
    const float aa = rstd * gamma[c];
    const float dd = beta[c] - mean * aa;
    const float* src = xb + (size_t)r * NN + n0 + cu * 8;
    float4 v0 = *(const float4*)src;
    float4 v1 = *(const float4*)(src + 4);
    uint4 pk;
    pk.x = pack2bf(fmaf(aa, v0.x, dd), fmaf(aa, v0.y, dd));
    pk.y = pack2bf(fmaf(aa, v0.z, dd), fmaf(aa, v0.w, dd));
    pk.z = pack2bf(fmaf(aa, v1.x, dd), fmaf(aa, v1.y, dd));
    pk.w = pack2bf(fmaf(aa, v1.z, dd), fmaf(aa, v1.w, dd));
    const int pu = cu ^ ((r >> 3) & 7);
    *(uint4*)((char*)Ts + r * 128 + pu * 16) = pk;
  }
  __syncthreads();
#pragma unroll
  for (int it = 0; it < 2; ++it) {
    const int U = it * 256 + t;
    const int n = U >> 3, cu2 = U & 7;
    bf16x8 v;
#pragma unroll
    for (int jj = 0; jj < 8; ++jj) {
      const int c = cu2 * 8 + jj;
      v[jj] = (short)Ts[c * 64 + (((n >> 3) ^ cu2) << 3) + (n & 7)];
    }
    *(bf16x8*)(hT + ((size_t)b * NN + n0 + n) * CC + c0 + cu2 * 8) = v;
  }
}

// ------------- w_qkv fp32 -> bf16 (one-shot, tiny) -------------
__global__ __launch_bounds__(256) void convert_w_kernel(const float* __restrict__ w,
                                                        u16* __restrict__ wb, int n8) {
  const int i = blockIdx.x * 256 + threadIdx.x;
  if (i >= n8) return;
  const float4 a = *(const float4*)(w + (size_t)i * 8);
  const float4 b = *(const float4*)(w + (size_t)i * 8 + 4);
  uint4 pk;
  pk.x = pack2bf(a.x, a.y);
  pk.y = pack2bf(a.z, a.w);
  pk.z = pack2bf(b.x, b.y);
  pk.w = pack2bf(b.z, b.w);
  *(uint4*)(wb + (size_t)i * 8) = pk;
}

// ------------- QKV GEMM on MFMA: qkv[o][n] = wbf[o][c] * hT[n][c]^T + bias -------------
__global__ __launch_bounds__(256) void qkv_mfma_kernel(
    const u16* __restrict__ hT, const u16* __restrict__ wbf,
    const float* __restrict__ bqkv, u16* __restrict__ qkv) {
  __shared__ __align__(16) u16 Asb[128 * 32 * 2];  // A tile | B tile, 16 KB
  u16* const Bsb = Asb + 128 * 32;
  const int b = blockIdx.z;
  const int o0 = blockIdx.y * 128;
  const int n0 = blockIdx.x * 128;
  const int t = threadIdx.x;
  const int w = t >> 6;
  const int lane = t & 63;
  const int quad = lane >> 4;
  const int m16 = lane & 15;
  const int wm = w >> 1, wn = w & 1;

  const int sr = lane >> 2;
  const int gu = (lane & 3) ^ ((lane >> 3) & 3);
  const u16* gA0 = wbf + (size_t)(o0 + w * 32 + sr) * CC + gu * 8;
  const u16* gA1 = gA0 + (size_t)16 * CC;
  const u16* hTb = hT + (size_t)b * NN * CC;
  const u16* gB0 = hTb + (size_t)(n0 + w * 32 + sr) * CC + gu * 8;
  const u16* gB1 = gB0 + (size_t)16 * CC;
  u16* const lA0 = Asb + (w * 32) * 32;
  u16* const lA1 = Asb + (w * 32 + 16) * 32;
  u16* const lB0 = Bsb + (w * 32) * 32;
  u16* const lB1 = Bsb + (w * 32 + 16) * 32;

  const int sfr = (m16 >> 1) & 3;
  const u16* aP[4];
  const u16* bP[4];
#pragma unroll
  for (int mt = 0; mt < 4; ++mt)
    aP[mt] = Asb + (wm * 64 + mt * 16 + m16) * 32 + (quad ^ sfr) * 8;
#pragma unroll
  for (int ct = 0; ct < 4; ++ct)
    bP[ct] = Bsb + (wn * 64 + ct * 16 + m16) * 32 + (quad ^ sfr) * 8;

  f32x4 acc[4][4];
#pragma unroll
  for (int mt = 0; mt < 4; ++mt)
#pragma unroll
    for (int ct = 0; ct < 4; ++ct) acc[mt][ct] = (f32x4){0.f, 0.f, 0.f, 0.f};

  for (int kk = 0; kk < 16; ++kk) {
    __syncthreads();
    gload_lds16(gA0, lA0);
    gload_lds16(gA1, lA1);
    gload_lds16(gB0, lB0);
    gload_lds16(gB1, lB1);
    gA0 += 32; gA1 += 32; gB0 += 32; gB1 += 32;
    __syncthreads();
    bf16x8 af[4], bfr[4];
#pragma unroll
    for (int mt = 0; mt < 4; ++mt) af[mt] = *(const bf16x8*)aP[mt];
#pragma unroll
    for (int ct = 0; ct < 4; ++ct) bfr[ct] = *(const bf16x8*)bP[ct];
#pragma unroll
    for (int mt = 0; mt < 4; ++mt)
#pragma unroll
      for (int ct = 0; ct < 4; ++ct)
        acc[mt][ct] = __builtin_amdgcn_mfma_f32_16x16x32_bf16(af[mt], bfr[ct],
                                                              acc[mt][ct], 0, 0, 0);
  }
  __syncthreads();

  u16* qb = qkv + (size_t)b * BATCH_STRIDE;
  size_t roff;
  int lo0;
  if (o0 < 512) { roff = Q_OFF; lo0 = o0; }
  else if (o0 < 1024) { roff = K_OFF; lo0 = o0 - 512; }
  else { roff = V_OFF; lo0 = o0 - 1024; }

  u16* const scr = Asb + w * 1024;
#pragma unroll
  for (int mt = 0; mt < 4; ++mt) {
#pragma unroll
    for (int ct = 0; ct < 4; ++ct) {
#pragma unroll
      for (int i = 0; i < 4; ++i) {
        const int row = quad * 4 + i;
        const int nn = ct * 16 + m16;
        const int pu = (nn >> 3) ^ ((row & 7) ^ (row >> 3));
        scr[row * 64 + pu * 8 + (nn & 7)] =
            f2bf(acc[mt][ct][i] + bqkv[o0 + wm * 64 + mt * 16 + row]);
      }
    }
    __syncthreads();
#pragma unroll
    for (int half = 0; half < 2; ++half) {
      const int idx = half * 64 + lane;
      const int row = idx >> 3;
      const int cu = idx & 7;
      const int pu = cu ^ ((row & 7) ^ (row >> 3));
      bf16x8 vv = *(const bf16x8*)(scr + row * 64 + pu * 8);
      *(bf16x8*)(qb + roff + (size_t)(lo0 + wm * 64 + mt * 16 + row) * NN +
                 n0 + wn * 64 + cu * 8) = vv;
    }
    __syncthreads();
  }
}

// ------------- 64x64 tile transpose q,k: [c][n] -> [n][c] bf16 -------------
__global__ __launch_bounds__(256) void transpose_qk_kernel(
    const u16* __restrict__ qkvbuf, u16* __restrict__ qT, u16* __restrict__ kT) {
  __shared__ __align__(16) u16 Ts[64 * 64];  // XOR-swizzled 16B units
  const int b = blockIdx.z >> 1;
  const int which = blockIdx.z & 1;
  const int c0 = blockIdx.y * 64;
  const int n0 = blockIdx.x * 64;
  const int t = threadIdx.x;
  const u16* src = qkvbuf + (size_t)b * BATCH_STRIDE + (which ? K_OFF : Q_OFF);
  u16* dst = (which ? kT : qT) + (size_t)b * (CC * NN);
#pragma unroll
  for (int it = 0; it < 2; ++it) {
    const int U = it * 256 + t;
    const int r = U >> 3, cu = U & 7;
    const int pu = cu ^ ((r >> 3) & 7);
    *(uint4*)((char*)Ts + r * 128 + pu * 16) =
        *(const uint4*)(src + (size_t)(c0 + r) * NN + n0 + cu * 8);
  }
  __syncthreads();
#pragma unroll
  for (int it = 0; it < 2; ++it) {
    const int U = it * 256 + t;
    const int n = U >> 3, cu2 = U & 7;
    bf16x8 v;
#pragma unroll
    for (int jj = 0; jj < 8; ++jj) {
      const int c = cu2 * 8 + jj;
      v[jj] = (short)Ts[c * 64 + (((n >> 3) ^ cu2) << 3) + (n & 7)];
    }
    *(bf16x8*)(dst + (size_t)(n0 + n) * CC + c0 + cu2 * 8) = v;
  }
}

// ------------- Flash attention, wave-local softmax (swapped QK^T), 1 barrier/iter ----
// 8 waves x 512 threads; wave w owns 16 q-rows, ALL 512 channels.
// amdgpu_waves_per_eu(1, 2): the MAX=2 arg is the budget-forcing knob -> 256
// unified regs/wave. R2-R6 evidence: launch_bounds' 2nd arg and one-arg
// waves_per_eu set only the MIN (a lower bound), leaving the allocator's
// default 128-reg budget -> ~100 regs spilled per iter = 3-17 GB scratch
// traffic. LDS (138 KB) already limits to 1 block/CU, so max 2 waves/EU
// costs nothing.
__global__ __attribute__((amdgpu_flat_work_group_size(512, 512),
                          amdgpu_waves_per_eu(1, 2))) void attn_mfma_kernel(
    u16* __restrict__ qkvbuf, const u16* __restrict__ qT, const u16* __restrict__ kT) {
  // Kt dbuf 2x32KB | Vt dbuf 2x32KB | Pb 8 x [16][40] u16
  __shared__ __align__(16) u16 smem[70656];
  u16* const KtA = smem;             // 16384 u16 each
  u16* const KtB = smem + 16384;
  u16* const VtA = smem + 32768;
  u16* const VtB = smem + 49152;
  u16* const Pbase = smem + 65536;   // 8 * 640 u16

  // XCD-aware: linear dispatch id % 8 selects XCD; bind batch to XCD.
  const int flat = blockIdx.y * 32 + blockIdx.x;   // grid = (32, 8)
  const int b = flat & 7;
  const int i0 = (flat >> 3) * 128;
  const int t = threadIdx.x;
  const int w = t >> 6;
  const int lane = t & 63;
  const int quad = lane >> 4;
  const int m16 = lane & 15;

  const u16* vb = qkvbuf + (size_t)b * BATCH_STRIDE + V_OFF;
  float* obuf = (float*)(qkvbuf + (size_t)b * BATCH_STRIDE + Q_OFF);  // aliases q+k
  const u16* qTb = qT + (size_t)b * (CC * NN);
  const u16* kTb = kT + (size_t)b * (CC * NN);
  u16* const myP = Pbase + w * 640;  // [16][40] wave-private

  const int vsrcu = ((lane & 3) ^ ((lane >> 2) & 3)) * 8;   // V source unit (u16)
  const int vrow = lane >> 2;                                // V row within seg

  // ---- prologue: stage tile 0 into buffer A ----
#pragma unroll
  for (int it = 0; it < 4; ++it) {
    const int j = it * 8 + w;
    gload_lds16(kTb + (size_t)j * CC + (lane ^ (j & 7)) * 8, KtA + j * 512 + lane * 8);
  }
#pragma unroll
  for (int it = 0; it < 4; ++it) {
    const int seg = it * 8 + w;
    const int c = seg * 16 + vrow;
    gload_lds16(vb + (size_t)c * NN + vsrcu, VtA + seg * 512 + lane * 8);
  }

  // Q fragments: 16 named bf16x8 registers (q row = i0 + w*16 + m16)
  const u16* qrow = qTb + (size_t)(i0 + w * 16 + m16) * CC + quad * 8;
#define QDECL(kc) bf16x8 q##kc = *(const bf16x8*)(qrow + kc * 32);
  FOR16(QDECL)
#undef QDECL

  float m_r = -1e30f, l_r = 0.f;  // per q-row (q=m16), replicated across quads
  // O accumulators: 32 named f32x4 (rows q=quad*4+r, col c=ct*16+m16)
#define ODECL(ct) f32x4 o##ct = (f32x4){0.f, 0.f, 0.f, 0.f};
  FOR32(ODECL)
#undef ODECL

  __syncthreads();  // tile 0 staged (vmcnt drained by all waves)

  for (int jt = 0; jt < NN / 32; ++jt) {
    const int cur = jt & 1;
    const u16* Ktc = cur ? KtB : KtA;
    const u16* Vtc = cur ? VtB : VtA;
    // ---- issue next-tile staging into the other buffer (overlaps compute) ----
    if (jt + 1 < NN / 32) {
      u16* Ktn = cur ? KtA : KtB;
      u16* Vtn = cur ? VtA : VtB;
      const int j0n = (jt + 1) * 32;
#pragma unroll
      for (int it = 0; it < 4; ++it) {
        const int j = it * 8 + w;
        gload_lds16(kTb + (size_t)(j0n + j) * CC + (lane ^ (j & 7)) * 8,
                    Ktn + j * 512 + lane * 8);
      }
#pragma unroll
      for (int it = 0; it < 4; ++it) {
        const int seg = it * 8 + w;
        const int c = seg * 16 + vrow;
        gload_lds16(vb + (size_t)c * NN + j0n + vsrcu, Vtn + seg * 512 + lane * 8);
      }
    }
    // ---- S^T = mfma(K, Q): two 16-key tiles, fully static ----
    f32x4 s0 = (f32x4){0.f, 0.f, 0.f, 0.f};
    f32x4 s1 = (f32x4){0.f, 0.f, 0.f, 0.f};
    {
      const u16* k0 = Ktc + m16 * 512;
      const u16* k1 = k0 + 16 * 512;
      const int sz = m16 & 7;
#define SSTEP(kc) { const int u = ((kc * 4 + quad) ^ sz) * 8; \
      bf16x8 ka = *(const bf16x8*)(k0 + u); \
      bf16x8 kb = *(const bf16x8*)(k1 + u); \
      s0 = __builtin_amdgcn_mfma_f32_16x16x32_bf16(ka, q##kc, s0, 0, 0, 0); \
      s1 = __builtin_amdgcn_mfma_f32_16x16x32_bf16(kb, q##kc, s1, 0, 0, 0); }
      FOR16(SSTEP)
#undef SSTEP
    }
    // ---- wave-local online softmax: lane holds 8 scores of q-row m16 ----
    float p0 = s0[0] * SCALE, p1 = s0[1] * SCALE, p2 = s0[2] * SCALE, p3 = s0[3] * SCALE;
    float p4 = s1[0] * SCALE, p5 = s1[1] * SCALE, p6 = s1[2] * SCALE, p7 = s1[3] * SCALE;
    float mx = fmaxf(fmaxf(fmaxf(p0, p1), fmaxf(p2, p3)),
                     fmaxf(fmaxf(p4, p5), fmaxf(p6, p7)));
    mx = fmaxf(mx, __shfl_xor(mx, 16));
    mx = fmaxf(mx, __shfl_xor(mx, 32));
    const float mold = m_r;
    const float mnew = fmaxf(mold, mx);
    m_r = mnew;
    const float alpha = __expf(mold - mnew);
    p0 = __expf(p0 - mnew); p1 = __expf(p1 - mnew);
    p2 = __expf(p2 - mnew); p3 = __expf(p3 - mnew);
    p4 = __expf(p4 - mnew); p5 = __expf(p5 - mnew);
    p6 = __expf(p6 - mnew); p7 = __expf(p7 - mnew);
    float sum = ((p0 + p1) + (p2 + p3)) + ((p4 + p5) + (p6 + p7));
    sum += __shfl_xor(sum, 16);
    sum += __shfl_xor(sum, 32);
    l_r = l_r * alpha + sum;
    // pack P (keys quad*4.., 16+quad*4..) into wave-private Pb[q=m16][key]
    uint2 pw0, pw1;
    pw0.x = pack2bf(p0, p1); pw0.y = pack2bf(p2, p3);
    pw1.x = pack2bf(p4, p5); pw1.y = pack2bf(p6, p7);
    *(uint2*)(myP + m16 * 40 + quad * 4) = pw0;
    *(uint2*)(myP + m16 * 40 + 16 + quad * 4) = pw1;
    asm volatile("s_waitcnt lgkmcnt(0)" ::: "memory");
    // A-frag for PV: P[q=m16][k = quad*8 + j]
    bf16x8 pf = *(const bf16x8*)(myP + m16 * 40 + quad * 8);
    // alpha for this lane's 4 output q-rows (quad*4+r)
    const float a0 = __shfl(alpha, quad * 4 + 0);
    const float a1 = __shfl(alpha, quad * 4 + 1);
    const float a2 = __shfl(alpha, quad * 4 + 2);
    const float a3 = __shfl(alpha, quad * 4 + 3);
    // ---- PV: O[16q][512c], B-frag V[k=key][n=c] from Vt [c][32] swizzled ----
    const u16* vbase = Vtc + m16 * 32 + (quad ^ (m16 & 3)) * 8;
    const bool nores = __all(mnew == mold);
#define PVN(ct) { bf16x8 vf = *(const bf16x8*)(vbase + ct * 512); \
      o##ct = __builtin_amdgcn_mfma_f32_16x16x32_bf16(pf, vf, o##ct, 0, 0, 0); }
#define PVR(ct) { bf16x8 vf = *(const bf16x8*)(vbase + ct * 512); \
      f32x4 oo = o##ct; oo[0] *= a0; oo[1] *= a1; oo[2] *= a2; oo[3] *= a3; \
      o##ct = __builtin_amdgcn_mfma_f32_16x16x32_bf16(pf, vf, oo, 0, 0, 0); }
    if (nores) {
      FOR32(PVN)
    } else {
      FOR32(PVR)
    }
#undef PVN
#undef PVR
    __syncthreads();  // all waves done with buf[cur]; buf[next] staged & visible
  }
  // ---- epilogue: direct stores; lane's 4 values are contiguous n-positions ----
  const float invl = 1.0f / l_r;
  const float il0 = __shfl(invl, quad * 4 + 0);
  const float il1 = __shfl(invl, quad * 4 + 1);
  const float il2 = __shfl(invl, quad * 4 + 2);
  const float il3 = __shfl(invl, quad * 4 + 3);
  const size_t ncol = i0 + w * 16 + quad * 4;
#define EPI(ct) { float4 ov; \
      ov.x = o##ct[0] * il0; ov.y = o##ct[1] * il1; \
      ov.z = o##ct[2] * il2; ov.w = o##ct[3] * il3; \
      *(float4*)(obuf + (size_t)(ct * 16 + m16) * NN + ncol) = ov; }
  FOR32(EPI)
#undef EPI
}

// ------------- output projection + bias + residual (obuf aliased in qkv ws) -------------
__global__ __launch_bounds__(256) void proj_kernel(
    const u16* __restrict__ qkvbuf, const float* __restrict__ wout,
    const float* __restrict__ bout, const float* __restrict__ x,
    float* __restrict__ out) {
  __shared__ __align__(16) float Wt[16][68];
  __shared__ __align__(16) float Ht[16][68];
  const int b = blockIdx.z;
  const int o0 = blockIdx.y * 64;
  const int n0 = blockIdx.x * 64;
  const int t = threadIdx.x;
  const int to = (t >> 4) * 4;
  const int tn = (t & 15) * 4;
  const int wo = t >> 2;
  const int wk = (t & 3) * 4;
  const int xc = t >> 4;
  const int xn = (t & 15) * 4;
  const float* ob = (const float*)(qkvbuf + (size_t)b * BATCH_STRIDE + Q_OFF);
  float acc[4][4] = {{0.f}};
  for (int kk = 0; kk < CC; kk += 16) {
    float4 wv = *(const float4*)(wout + (size_t)(o0 + wo) * CC + kk + wk);
    float4 hv = *(const float4*)(ob + (size_t)(kk + xc) * NN + n0 + xn);
    __syncthreads();
    Wt[wk + 0][wo] = wv.x;
    Wt[wk + 1][wo] = wv.y;
    Wt[wk + 2][wo] = wv.z;
    Wt[wk + 3][wo] = wv.w;
    *(float4*)&Ht[xc][xn] = hv;
    __syncthreads();
#pragma unroll
    for (int k = 0; k < 16; ++k) {
      float4 w4 = *(const float4*)&Wt[k][to];
      float4 h4 = *(const float4*)&Ht[k][tn];
      acc[0][0] = fmaf(w4.x, h4.x, acc[0][0]);
      acc[0][1] = fmaf(w4.x, h4.y, acc[0][1]);
      acc[0][2] = fmaf(w4.x, h4.z, acc[0][2]);
      acc[0][3] = fmaf(w4.x, h4.w, acc[0][3]);
      acc[1][0] = fmaf(w4.y, h4.x, acc[1][0]);
      acc[1][1] = fmaf(w4.y, h4.y, acc[1][1]);
      acc[1][2] = fmaf(w4.y, h4.z, acc[1][2]);
      acc[1][3] = fmaf(w4.y, h4.w, acc[1][3]);
      acc[2][0] = fmaf(w4.z, h4.x, acc[2][0]);
      acc[2][1] = fmaf(w4.z, h4.y, acc[2][1]);
      acc[2][2] = fmaf(w4.z, h4.z, acc[2][2]);
      acc[2][3] = fmaf(w4.z, h4.w, acc[2][3]);
      acc[3][0] = fmaf(w4.w, h4.x, acc[3][0]);
      acc[3][1] = fmaf(w4.w, h4.y, acc[3][1]);
      acc[3][2] = fmaf(w4.w, h4.z, acc[3][2]);
      acc[3][3] = fmaf(w4.w, h4.w, acc[3][3]);
    }
  }
#pragma unroll
  for (int i = 0; i < 4; ++i) {
    const int o = o0 + to + i;
    const float bias = bout[o];
    const size_t idx = ((size_t)b * CC + o) * NN + n0 + tn;
    float4 xv = *(const float4*)(x + idx);
    float4 r;
    r.x = acc[i][0] + bias + xv.x;
    r.y = acc[i][1] + bias + xv.y;
    r.z = acc[i][2] + bias + xv.z;
    r.w = acc[i][3] + bias + xv.w;
    *(float4*)(out + idx) = r;
  }
}

extern "C" void kernel_launch(void* const* d_in, const int* in_sizes, int n_in,
                              void* d_out, int out_size, void* d_ws, size_t ws_size,
                              hipStream_t stream) {
  const float* x = (const float*)d_in[0];
  const float* gamma = (const float*)d_in[1];
  const float* beta = (const float*)d_in[2];
  const float* wqkv = (const float*)d_in[3];
  const float* bqkv = (const float*)d_in[4];
  const float* wout = (const float*)d_in[5];
  const float* bout = (const float*)d_in[6];
  float* out = (float*)d_out;

  char* ws = (char*)d_ws;
  float* stats = (float*)ws;                           // 2 KB
  u16* qkv = (u16*)(ws + 4096);                        // bf16 [v|q|k] per batch
  u16* qT = (u16*)(ws + 4096 + (size_t)BB * OQKV * NN * 2);      // 33.55 MB
  u16* kT = qT + (size_t)BB * CC * NN;                            // 33.55 MB
  u16* hT = qT;    // alias: [B][N][C] bf16, consumed before transpose_qk writes qT
  u16* wbf = kT;   // alias: [1536][512] bf16

  gn_stats_kernel<<<BB * GG, 256, 0, stream>>>(x, stats);
  gn_transpose_kernel<<<dim3(NN / 64, CC / 64, BB), 256, 0, stream>>>(
      x, gamma, beta, stats, hT);
  convert_w_kernel<<<(OQKV * CC / 8 + 255) / 256, 256, 0, stream>>>(
      wqkv, wbf, OQKV * CC / 8);
  qkv_mfma_kernel<<<dim3(NN / 128, OQKV / 128, BB), 256, 0, stream>>>(
      hT, wbf, bqkv, qkv);
  transpose_qk_kernel<<<dim3(NN / 64, CC / 64, BB * 2), 256, 0, stream>>>(qkv, qT, kT);
  attn_mfma_kernel<<<dim3(NN / 128, BB), 512, 0, stream>>>(qkv, qT, kT);
  proj_kernel<<<dim3(NN / 64, CC / 64, BB), 256, 0, stream>>>(qkv, wout, bout, x, out);
}

// Round 8
// 1843.446 us; speedup vs baseline: 2.7172x; 1.3369x over previous
//
#include <hip/hip_runtime.h>

#define BB 8
#define CC 512
#define NN 4096
#define GG 32
#define OQKV 1536
#define EPSV 1e-5f
#define SCALE 0.044194173824159216f  // 1/sqrt(512)

// per-batch u16 offsets inside the qkv workspace region: [v | q | k]
#define BATCH_STRIDE 6291456u   // 1536*4096
#define V_OFF 0u
#define Q_OFF 2097152u          // 512*4096
#define K_OFF 4194304u

typedef unsigned short u16;
typedef unsigned int u32;
typedef __attribute__((ext_vector_type(8))) short bf16x8;
typedef __attribute__((ext_vector_type(4))) float f32x4;

#define FOR16(OP) OP(0) OP(1) OP(2) OP(3) OP(4) OP(5) OP(6) OP(7) \
                  OP(8) OP(9) OP(10) OP(11) OP(12) OP(13) OP(14) OP(15)

__device__ __forceinline__ u16 f2bf(float f) {
  u32 u = __float_as_uint(f);
  u32 r = (u + 0x7FFFu + ((u >> 16) & 1u)) >> 16;  // RNE
  return (u16)r;
}

__device__ __forceinline__ u32 pack2bf(float a, float b) {
  return (u32)f2bf(a) | ((u32)f2bf(b) << 16);
}

__device__ __forceinline__ void gload_lds16(const u16* g, u16* l) {
  __builtin_amdgcn_global_load_lds(
      (const __attribute__((address_space(1))) u32*)(g),
      (__attribute__((address_space(3))) u32*)(l), 16, 0, 0);
}

// ---------------- GroupNorm statistics: one block per (b, group) ----------------
__global__ __launch_bounds__(256) void gn_stats_kernel(const float* __restrict__ x,
                                                       float* __restrict__ stats) {
  const int bg = blockIdx.x;
  const float4* xp = (const float4*)(x + (size_t)bg * 16 * NN);
  const int n4 = 16 * NN / 4;
  float s = 0.f, ss = 0.f;
  for (int i = threadIdx.x; i < n4; i += 256) {
    float4 v = xp[i];
    s += v.x + v.y + v.z + v.w;
    ss += v.x * v.x + v.y * v.y + v.z * v.z + v.w * v.w;
  }
  for (int off = 32; off > 0; off >>= 1) {
    s += __shfl_down(s, off, 64);
    ss += __shfl_down(ss, off, 64);
  }
  __shared__ float rs[4], rss[4];
  const int wid = threadIdx.x >> 6, lane = threadIdx.x & 63;
  if (lane == 0) { rs[wid] = s; rss[wid] = ss; }
  __syncthreads();
  if (threadIdx.x == 0) {
    float S = rs[0] + rs[1] + rs[2] + rs[3];
    float SS = rss[0] + rss[1] + rss[2] + rss[3];
    const float invn = 1.0f / (16.0f * NN);
    float mean = S * invn;
    float var = SS * invn - mean * mean;
    stats[bg * 2] = mean;
    stats[bg * 2 + 1] = rsqrtf(var + EPSV);
  }
}

// ------------- GN-apply + transpose: x [C][N] fp32 -> hT [N][C] bf16 -------------
__global__ __launch_bounds__(256) void gn_transpose_kernel(
    const float* __restrict__ x, const float* __restrict__ gamma,
    const float* __restrict__ beta, const float* __restrict__ stats,
    u16* __restrict__ hT) {
  __shared__ __align__(16) u16 Ts[64 * 64];  // XOR-swizzled 16B units
  const int b = blockIdx.z;
  const int c0 = blockIdx.y * 64;
  const int n0 = blockIdx.x * 64;
  const int t = threadIdx.x;
  const float* xb = x + ((size_t)b * CC + c0) * NN;
#pragma unroll
  for (int it = 0; it < 2; ++it) {
    const int U = it * 256 + t;
    const int r = U >> 3, cu = U & 7;  // r = channel row, cu = 8-elem n unit
    const int c = c0 + r;
    const int g = c >> 4;
    const float mean = stats[(b * GG + g) * 2];
    const float rstd = stats[(b * GG + g) * 2 + 1];
    const float aa = rstd * gamma[c];
    const float dd = beta[c] - mean * aa;
    const float* src = xb + (size_t)r * NN + n0 + cu * 8;
    float4 v0 = *(const float4*)src;
    float4 v1 = *(const float4*)(src + 4);
    uint4 pk;
    pk.x = pack2bf(fmaf(aa, v0.x, dd), fmaf(aa, v0.y, dd));
    pk.y = pack2bf(fmaf(aa, v0.z, dd), fmaf(aa, v0.w, dd));
    pk.z = pack2bf(fmaf(aa, v1.x, dd), fmaf(aa, v1.y, dd));
    pk.w = pack2bf(fmaf(aa, v1.z, dd), fmaf(aa, v1.w, dd));
    const int pu = cu ^ ((r >> 3) & 7);
    *(uint4*)((char*)Ts + r * 128 + pu * 16) = pk;
  }
  __syncthreads();
#pragma unroll
  for (int it = 0; it < 2; ++it) {
    const int U = it * 256 + t;
    const int n = U >> 3, cu2 = U & 7;
    bf16x8 v;
#pragma unroll
    for (int jj = 0; jj < 8; ++jj) {
      const int c = cu2 * 8 + jj;
      v[jj] = (short)Ts[c * 64 + (((n >> 3) ^ cu2) << 3) + (n & 7)];
    }
    *(bf16x8*)(hT + ((size_t)b * NN + n0 + n) * CC + c0 + cu2 * 8) = v;
  }
}

// ------------- w_qkv fp32 -> bf16 (one-shot, tiny) -------------
__global__ __launch_bounds__(256) void convert_w_kernel(const float* __restrict__ w,
                                                        u16* __restrict__ wb, int n8) {
  const int i = blockIdx.x * 256 + threadIdx.x;
  if (i >= n8) return;
  const float4 a = *(const float4*)(w + (size_t)i * 8);
  const float4 b = *(const float4*)(w + (size_t)i * 8 + 4);
  uint4 pk;
  pk.x = pack2bf(a.x, a.y);
  pk.y = pack2bf(a.z, a.w);
  pk.z = pack2bf(b.x, b.y);
  pk.w = pack2bf(b.z, b.w);
  *(uint4*)(wb + (size_t)i * 8) = pk;
}

// ------------- QKV GEMM on MFMA: qkv[o][n] = wbf[o][c] * hT[n][c]^T + bias -------------
__global__ __launch_bounds__(256) void qkv_mfma_kernel(
    const u16* __restrict__ hT, const u16* __restrict__ wbf,
    const float* __restrict__ bqkv, u16* __restrict__ qkv) {
  __shared__ __align__(16) u16 Asb[128 * 32 * 2];  // A tile | B tile, 16 KB
  u16* const Bsb = Asb + 128 * 32;
  const int b = blockIdx.z;
  const int o0 = blockIdx.y * 128;
  const int n0 = blockIdx.x * 128;
  const int t = threadIdx.x;
  const int w = t >> 6;
  const int lane = t & 63;
  const int quad = lane >> 4;
  const int m16 = lane & 15;
  const int wm = w >> 1, wn = w & 1;

  const int sr = lane >> 2;
  const int gu = (lane & 3) ^ ((lane >> 3) & 3);
  const u16* gA0 = wbf + (size_t)(o0 + w * 32 + sr) * CC + gu * 8;
  const u16* gA1 = gA0 + (size_t)16 * CC;
  const u16* hTb = hT + (size_t)b * NN * CC;
  const u16* gB0 = hTb + (size_t)(n0 + w * 32 + sr) * CC + gu * 8;
  const u16* gB1 = gB0 + (size_t)16 * CC;
  u16* const lA0 = Asb + (w * 32) * 32;
  u16* const lA1 = Asb + (w * 32 + 16) * 32;
  u16* const lB0 = Bsb + (w * 32) * 32;
  u16* const lB1 = Bsb + (w * 32 + 16) * 32;

  const int sfr = (m16 >> 1) & 3;
  const u16* aP[4];
  const u16* bP[4];
#pragma unroll
  for (int mt = 0; mt < 4; ++mt)
    aP[mt] = Asb + (wm * 64 + mt * 16 + m16) * 32 + (quad ^ sfr) * 8;
#pragma unroll
  for (int ct = 0; ct < 4; ++ct)
    bP[ct] = Bsb + (wn * 64 + ct * 16 + m16) * 32 + (quad ^ sfr) * 8;

  f32x4 acc[4][4];
#pragma unroll
  for (int mt = 0; mt < 4; ++mt)
#pragma unroll
    for (int ct = 0; ct < 4; ++ct) acc[mt][ct] = (f32x4){0.f, 0.f, 0.f, 0.f};

  for (int kk = 0; kk < 16; ++kk) {
    __syncthreads();
    gload_lds16(gA0, lA0);
    gload_lds16(gA1, lA1);
    gload_lds16(gB0, lB0);
    gload_lds16(gB1, lB1);
    gA0 += 32; gA1 += 32; gB0 += 32; gB1 += 32;
    __syncthreads();
    bf16x8 af[4], bfr[4];
#pragma unroll
    for (int mt = 0; mt < 4; ++mt) af[mt] = *(const bf16x8*)aP[mt];
#pragma unroll
    for (int ct = 0; ct < 4; ++ct) bfr[ct] = *(const bf16x8*)bP[ct];
#pragma unroll
    for (int mt = 0; mt < 4; ++mt)
#pragma unroll
      for (int ct = 0; ct < 4; ++ct)
        acc[mt][ct] = __builtin_amdgcn_mfma_f32_16x16x32_bf16(af[mt], bfr[ct],
                                                              acc[mt][ct], 0, 0, 0);
  }
  __syncthreads();

  u16* qb = qkv + (size_t)b * BATCH_STRIDE;
  size_t roff;
  int lo0;
  if (o0 < 512) { roff = Q_OFF; lo0 = o0; }
  else if (o0 < 1024) { roff = K_OFF; lo0 = o0 - 512; }
  else { roff = V_OFF; lo0 = o0 - 1024; }

  u16* const scr = Asb + w * 1024;
#pragma unroll
  for (int mt = 0; mt < 4; ++mt) {
#pragma unroll
    for (int ct = 0; ct < 4; ++ct) {
#pragma unroll
      for (int i = 0; i < 4; ++i) {
        const int row = quad * 4 + i;
        const int nn = ct * 16 + m16;
        const int pu = (nn >> 3) ^ ((row & 7) ^ (row >> 3));
        scr[row * 64 + pu * 8 + (nn & 7)] =
            f2bf(acc[mt][ct][i] + bqkv[o0 + wm * 64 + mt * 16 + row]);
      }
    }
    __syncthreads();
#pragma unroll
    for (int half = 0; half < 2; ++half) {
      const int idx = half * 64 + lane;
      const int row = idx >> 3;
      const int cu = idx & 7;
      const int pu = cu ^ ((row & 7) ^ (row >> 3));
      bf16x8 vv = *(const bf16x8*)(scr + row * 64 + pu * 8);
      *(bf16x8*)(qb + roff + (size_t)(lo0 + wm * 64 + mt * 16 + row) * NN +
                 n0 + wn * 64 + cu * 8) = vv;
    }
    __syncthreads();
  }
}

// ------------- 64x64 tile transpose q,k: [c][n] -> [n][c] bf16 -------------
__global__ __launch_bounds__(256) void transpose_qk_kernel(
    const u16* __restrict__ qkvbuf, u16* __restrict__ qT, u16* __restrict__ kT) {
  __shared__ __align__(16) u16 Ts[64 * 64];  // XOR-swizzled 16B units
  const int b = blockIdx.z >> 1;
  const int which = blockIdx.z & 1;
  const int c0 = blockIdx.y * 64;
  const int n0 = blockIdx.x * 64;
  const int t = threadIdx.x;
  const u16* src = qkvbuf + (size_t)b * BATCH_STRIDE + (which ? K_OFF : Q_OFF);
  u16* dst = (which ? kT : qT) + (size_t)b * (CC * NN);
#pragma unroll
  for (int it = 0; it < 2; ++it) {
    const int U = it * 256 + t;
    const int r = U >> 3, cu = U & 7;
    const int pu = cu ^ ((r >> 3) & 7);
    *(uint4*)((char*)Ts + r * 128 + pu * 16) =
        *(const uint4*)(src + (size_t)(c0 + r) * NN + n0 + cu * 8);
  }
  __syncthreads();
#pragma unroll
  for (int it = 0; it < 2; ++it) {
    const int U = it * 256 + t;
    const int n = U >> 3, cu2 = U & 7;
    bf16x8 v;
#pragma unroll
    for (int jj = 0; jj < 8; ++jj) {
      const int c = cu2 * 8 + jj;
      v[jj] = (short)Ts[c * 64 + (((n >> 3) ^ cu2) << 3) + (n & 7)];
    }
    *(bf16x8*)(dst + (size_t)(n0 + n) * CC + c0 + cu2 * 8) = v;
  }
}

// ------------- Flash attention v8: BQ=64, register demand <= ~115 (no spill) ----
// 8 waves x 512 threads; wave w = (wq = w>>1, wc = w&1): 16 q-rows (q-tile wq) x
// 256 channels (half wc). oacc = 16 f32x4 = 64 VGPR (was 32/128 -> spilled at the
// toolchain's immovable 128-reg budget, R2-R7). Q lives in LDS (64 KB, staged once
// via gload_lds, row-XOR swizzle) and is re-read per tile; QK^T is duplicated by
// the wave pair (MFMA util ~5% -> free). K,V single-buffered 32 KB each,
// T14 reg-staged: loads issued after S-phase, ds_write after the barrier.
__global__ __launch_bounds__(512, 1) void attn_mfma_kernel(
    u16* __restrict__ qkvbuf, const u16* __restrict__ qT, const u16* __restrict__ kT) {
  // Qs 64K | Kt 32K | Vt 32K | P 10K = 141312 B
  __shared__ __align__(16) u16 smem[70656];
  u16* const Qs = smem;              // [64 q][512 c], row-swizzled units
  u16* const Kt = smem + 32768;      // [32 k][512 c], row-swizzled units
  u16* const Vt = smem + 49152;      // [32 seg][512]: seg = c>>4, swizzled units
  u16* const Pbase = smem + 65536;   // 8 waves x [16][40] u16

  // XCD-aware: HW linear id % 8 = blockIdx.x % 8 -> bind batch to XCD.
  const int flat = blockIdx.y * 64 + blockIdx.x;   // grid = (64, 8)
  const int b = flat & 7;
  const int i0 = (flat >> 3) * 64;
  const int t = threadIdx.x;
  const int w = t >> 6;
  const int lane = t & 63;
  const int quad = lane >> 4;
  const int m16 = lane & 15;
  const int wq = w >> 1;   // q-tile 0..3
  const int wc = w & 1;    // channel half

  const u16* vb = qkvbuf + (size_t)b * BATCH_STRIDE + V_OFF;
  float* obuf = (float*)(qkvbuf + (size_t)b * BATCH_STRIDE + Q_OFF);  // aliases q+k
  const u16* qTb = qT + (size_t)b * (CC * NN);
  const u16* kTb = kT + (size_t)b * (CC * NN);
  u16* const myP = Pbase + w * 640;  // [16][40] wave-private

  const int vsrcu = ((lane & 3) ^ ((lane >> 2) & 3)) * 8;   // V source unit (u16)
  const int vrow = lane >> 2;                                // V row within seg

  // ---- prologue: stage Q (once) + tile 0 of K,V ----
#pragma unroll
  for (int it = 0; it < 8; ++it) {
    const int r = it * 8 + w;
    gload_lds16(qTb + (size_t)(i0 + r) * CC + (lane ^ (r & 7)) * 8,
                Qs + r * 512 + lane * 8);
  }
  uint4 kst[4], vst[4];
#pragma unroll
  for (int it = 0; it < 4; ++it) {
    const int j = it * 8 + w;
    kst[it] = *(const uint4*)(kTb + (size_t)j * CC + (lane ^ (j & 7)) * 8);
  }
#pragma unroll
  for (int it = 0; it < 4; ++it) {
    const int c = (it * 8 + w) * 16 + vrow;
    vst[it] = *(const uint4*)(vb + (size_t)c * NN + vsrcu);
  }
#pragma unroll
  for (int it = 0; it < 4; ++it)
    *(uint4*)(Kt + (it * 8 + w) * 512 + lane * 8) = kst[it];
#pragma unroll
  for (int it = 0; it < 4; ++it)
    *(uint4*)(Vt + (it * 8 + w) * 512 + lane * 8) = vst[it];

  float m_r = -1e30f, l_r = 0.f;  // per q-row (q=m16), replicated across quads
#define ODECL(ct) f32x4 o##ct = (f32x4){0.f, 0.f, 0.f, 0.f};
  FOR16(ODECL)
#undef ODECL

  __syncthreads();  // Q gload drained + tile 0 K/V visible

  const u16* const Qrow = Qs + (wq * 16 + m16) * 512;
  const u16* const k0 = Kt + m16 * 512;
  const u16* const k1 = k0 + 16 * 512;
  const u16* const vbase = Vt + wc * 8192 + m16 * 32 + (quad ^ (m16 & 3)) * 8;
  const int sz = m16 & 7;

  for (int jt = 0; jt < NN / 32; ++jt) {
    // ---- S^T = mfma(K, Q): two 16-key tiles; Q frag re-read from LDS ----
    f32x4 s0 = (f32x4){0.f, 0.f, 0.f, 0.f};
    f32x4 s1 = (f32x4){0.f, 0.f, 0.f, 0.f};
#define SSTEP(kc) { const int u = ((kc * 4 + quad) ^ sz) * 8; \
      bf16x8 qf = *(const bf16x8*)(Qrow + u); \
      bf16x8 ka = *(const bf16x8*)(k0 + u); \
      bf16x8 kb = *(const bf16x8*)(k1 + u); \
      s0 = __builtin_amdgcn_mfma_f32_16x16x32_bf16(ka, qf, s0, 0, 0, 0); \
      s1 = __builtin_amdgcn_mfma_f32_16x16x32_bf16(kb, qf, s1, 0, 0, 0); }
    FOR16(SSTEP)
#undef SSTEP
    // ---- issue next-tile K/V loads (land during softmax+PV; written post-barrier) ----
    if (jt + 1 < NN / 32) {
      const int j0n = (jt + 1) * 32;
#pragma unroll
      for (int it = 0; it < 4; ++it) {
        const int j = it * 8 + w;
        kst[it] = *(const uint4*)(kTb + (size_t)(j0n + j) * CC + (lane ^ (j & 7)) * 8);
      }
#pragma unroll
      for (int it = 0; it < 4; ++it) {
        const int c = (it * 8 + w) * 16 + vrow;
        vst[it] = *(const uint4*)(vb + (size_t)c * NN + j0n + vsrcu);
      }
    }
    // ---- wave-local online softmax: lane holds 8 scores of q-row m16 ----
    float p0 = s0[0] * SCALE, p1 = s0[1] * SCALE, p2 = s0[2] * SCALE, p3 = s0[3] * SCALE;
    float p4 = s1[0] * SCALE, p5 = s1[1] * SCALE, p6 = s1[2] * SCALE, p7 = s1[3] * SCALE;
    float mx = fmaxf(fmaxf(fmaxf(p0, p1), fmaxf(p2, p3)),
                     fmaxf(fmaxf(p4, p5), fmaxf(p6, p7)));
    mx = fmaxf(mx, __shfl_xor(mx, 16));
    mx = fmaxf(mx, __shfl_xor(mx, 32));
    const float mold = m_r;
    const float mnew = fmaxf(mold, mx);
    m_r = mnew;
    const float alpha = __expf(mold - mnew);
    p0 = __expf(p0 - mnew); p1 = __expf(p1 - mnew);
    p2 = __expf(p2 - mnew); p3 = __expf(p3 - mnew);
    p4 = __expf(p4 - mnew); p5 = __expf(p5 - mnew);
    p6 = __expf(p6 - mnew); p7 = __expf(p7 - mnew);
    float sum = ((p0 + p1) + (p2 + p3)) + ((p4 + p5) + (p6 + p7));
    sum += __shfl_xor(sum, 16);
    sum += __shfl_xor(sum, 32);
    l_r = l_r * alpha + sum;
    // pack P into wave-private Pb[q=m16][key]
    uint2 pw0, pw1;
    pw0.x = pack2bf(p0, p1); pw0.y = pack2bf(p2, p3);
    pw1.x = pack2bf(p4, p5); pw1.y = pack2bf(p6, p7);
    *(uint2*)(myP + m16 * 40 + quad * 4) = pw0;
    *(uint2*)(myP + m16 * 40 + 16 + quad * 4) = pw1;
    asm volatile("s_waitcnt lgkmcnt(0)" ::: "memory");
    // A-frag for PV: P[q=m16][k = quad*8 + j]
    bf16x8 pf = *(const bf16x8*)(myP + m16 * 40 + quad * 8);
    const float a0 = __shfl(alpha, quad * 4 + 0);
    const float a1 = __shfl(alpha, quad * 4 + 1);
    const float a2 = __shfl(alpha, quad * 4 + 2);
    const float a3 = __shfl(alpha, quad * 4 + 3);
    // ---- PV: O[16q][256c-half]; V frags from wave's 16 segs ----
    const bool nores = __all(mnew == mold);
#define PVN(ct) { bf16x8 vf = *(const bf16x8*)(vbase + ct * 512); \
      o##ct = __builtin_amdgcn_mfma_f32_16x16x32_bf16(pf, vf, o##ct, 0, 0, 0); }
#define PVR(ct) { bf16x8 vf = *(const bf16x8*)(vbase + ct * 512); \
      f32x4 oo = o##ct; oo[0] *= a0; oo[1] *= a1; oo[2] *= a2; oo[3] *= a3; \
      o##ct = __builtin_amdgcn_mfma_f32_16x16x32_bf16(pf, vf, oo, 0, 0, 0); }
    if (nores) {
      FOR16(PVN)
    } else {
      FOR16(PVR)
    }
#undef PVN
#undef PVR
    __syncthreads();  // all waves done reading Kt/Vt for this tile
    if (jt + 1 < NN / 32) {
#pragma unroll
      for (int it = 0; it < 4; ++it)
        *(uint4*)(Kt + (it * 8 + w) * 512 + lane * 8) = kst[it];
#pragma unroll
      for (int it = 0; it < 4; ++it)
        *(uint4*)(Vt + (it * 8 + w) * 512 + lane * 8) = vst[it];
    }
    __syncthreads();  // next tile visible
  }
  // ---- epilogue: direct stores; lane's 4 values are contiguous n-positions ----
  const float invl = 1.0f / l_r;
  const float il0 = __shfl(invl, quad * 4 + 0);
  const float il1 = __shfl(invl, quad * 4 + 1);
  const float il2 = __shfl(invl, quad * 4 + 2);
  const float il3 = __shfl(invl, quad * 4 + 3);
  const size_t ncol = i0 + wq * 16 + quad * 4;
#define EPI(ct) { float4 ov; \
      ov.x = o##ct[0] * il0; ov.y = o##ct[1] * il1; \
      ov.z = o##ct[2] * il2; ov.w = o##ct[3] * il3; \
      *(float4*)(obuf + (size_t)(wc * 256 + ct * 16 + m16) * NN + ncol) = ov; }
  FOR16(EPI)
#undef EPI
}

// ------------- output projection + bias + residual (obuf aliased in qkv ws) -------------
__global__ __launch_bounds__(256) void proj_kernel(
    const u16* __restrict__ qkvbuf, const float* __restrict__ wout,
    const float* __restrict__ bout, const float* __restrict__ x,
    float* __restrict__ out) {
  __shared__ __align__(16) float Wt[16][68];
  __shared__ __align__(16) float Ht[16][68];
  const int b = blockIdx.z;
  const int o0 = blockIdx.y * 64;
  const int n0 = blockIdx.x * 64;
  const int t = threadIdx.x;
  const int to = (t >> 4) * 4;
  const int tn = (t & 15) * 4;
  const int wo = t >> 2;
  const int wk = (t & 3) * 4;
  const int xc = t >> 4;
  const int xn = (t & 15) * 4;
  const float* ob = (const float*)(qkvbuf + (size_t)b * BATCH_STRIDE + Q_OFF);
  float acc[4][4] = {{0.f}};
  for (int kk = 0; kk < CC; kk += 16) {
    float4 wv = *(const float4*)(wout + (size_t)(o0 + wo) * CC + kk + wk);
    float4 hv = *(const float4*)(ob + (size_t)(kk + xc) * NN + n0 + xn);
    __syncthreads();
    Wt[wk + 0][wo] = wv.x;
    Wt[wk + 1][wo] = wv.y;
    Wt[wk + 2][wo] = wv.z;
    Wt[wk + 3][wo] = wv.w;
    *(float4*)&Ht[xc][xn] = hv;
    __syncthreads();
#pragma unroll
    for (int k = 0; k < 16; ++k) {
      float4 w4 = *(const float4*)&Wt[k][to];
      float4 h4 = *(const float4*)&Ht[k][tn];
      acc[0][0] = fmaf(w4.x, h4.x, acc[0][0]);
      acc[0][1] = fmaf(w4.x, h4.y, acc[0][1]);
      acc[0][2] = fmaf(w4.x, h4.z, acc[0][2]);
      acc[0][3] = fmaf(w4.x, h4.w, acc[0][3]);
      acc[1][0] = fmaf(w4.y, h4.x, acc[1][0]);
      acc[1][1] = fmaf(w4.y, h4.y, acc[1][1]);
      acc[1][2] = fmaf(w4.y, h4.z, acc[1][2]);
      acc[1][3] = fmaf(w4.y, h4.w, acc[1][3]);
      acc[2][0] = fmaf(w4.z, h4.x, acc[2][0]);
      acc[2][1] = fmaf(w4.z, h4.y, acc[2][1]);
      acc[2][2] = fmaf(w4.z, h4.z, acc[2][2]);
      acc[2][3] = fmaf(w4.z, h4.w, acc[2][3]);
      acc[3][0] = fmaf(w4.w, h4.x, acc[3][0]);
      acc[3][1] = fmaf(w4.w, h4.y, acc[3][1]);
      acc[3][2] = fmaf(w4.w, h4.z, acc[3][2]);
      acc[3][3] = fmaf(w4.w, h4.w, acc[3][3]);
    }
  }
#pragma unroll
  for (int i = 0; i < 4; ++i) {
    const int o = o0 + to + i;
    const float bias = bout[o];
    const size_t idx = ((size_t)b * CC + o) * NN + n0 + tn;
    float4 xv = *(const float4*)(x + idx);
    float4 r;
    r.x = acc[i][0] + bias + xv.x;
    r.y = acc[i][1] + bias + xv.y;
    r.z = acc[i][2] + bias + xv.z;
    r.w = acc[i][3] + bias + xv.w;
    *(float4*)(out + idx) = r;
  }
}

extern "C" void kernel_launch(void* const* d_in, const int* in_sizes, int n_in,
                              void* d_out, int out_size, void* d_ws, size_t ws_size,
                              hipStream_t stream) {
  const float* x = (const float*)d_in[0];
  const float* gamma = (const float*)d_in[1];
  const float* beta = (const float*)d_in[2];
  const float* wqkv = (const float*)d_in[3];
  const float* bqkv = (const float*)d_in[4];
  const float* wout = (const float*)d_in[5];
  const float* bout = (const float*)d_in[6];
  float* out = (float*)d_out;

  char* ws = (char*)d_ws;
  float* stats = (float*)ws;                           // 2 KB
  u16* qkv = (u16*)(ws + 4096);                        // bf16 [v|q|k] per batch
  u16* qT = (u16*)(ws + 4096 + (size_t)BB * OQKV * NN * 2);      // 33.55 MB
  u16* kT = qT + (size_t)BB * CC * NN;                            // 33.55 MB
  u16* hT = qT;    // alias: [B][N][C] bf16, consumed before transpose_qk writes qT
  u16* wbf = kT;   // alias: [1536][512] bf16

  gn_stats_kernel<<<BB * GG, 256, 0, stream>>>(x, stats);
  gn_transpose_kernel<<<dim3(NN / 64, CC / 64, BB), 256, 0, stream>>>(
      x, gamma, beta, stats, hT);
  convert_w_kernel<<<(OQKV * CC / 8 + 255) / 256, 256, 0, stream>>>(
      wqkv, wbf, OQKV * CC / 8);
  qkv_mfma_kernel<<<dim3(NN / 128, OQKV / 128, BB), 256, 0, stream>>>(
      hT, wbf, bqkv, qkv);
  transpose_qk_kernel<<<dim3(NN / 64, CC / 64, BB * 2), 256, 0, stream>>>(qkv, qT, kT);
  attn_mfma_kernel<<<dim3(NN / 64, BB), 512, 0, stream>>>(qkv, qT, kT);
  proj_kernel<<<dim3(NN / 64, CC / 64, BB), 256, 0, stream>>>(qkv, wout, bout, x, out);
}

// Round 9
// 1802.504 us; speedup vs baseline: 2.7790x; 1.0227x over previous
//
#include <hip/hip_runtime.h>

#define BB 8
#define CC 512
#define NN 4096
#define GG 32
#define OQKV 1536
#define EPSV 1e-5f
#define SCALE 0.044194173824159216f  // 1/sqrt(512)

// per-batch u16 offsets inside the qkv workspace region: [v | q | k]
#define BATCH_STRIDE 6291456u   // 1536*4096
#define V_OFF 0u
#define Q_OFF 2097152u          // 512*4096
#define K_OFF 4194304u

typedef unsigned short u16;
typedef unsigned int u32;
typedef __attribute__((ext_vector_type(8))) short bf16x8;
typedef __attribute__((ext_vector_type(4))) float f32x4;

#define FOR16(OP) OP(0) OP(1) OP(2) OP(3) OP(4) OP(5) OP(6) OP(7) \
                  OP(8) OP(9) OP(10) OP(11) OP(12) OP(13) OP(14) OP(15)

__device__ __forceinline__ u16 f2bf(float f) {
  u32 u = __float_as_uint(f);
  u32 r = (u + 0x7FFFu + ((u >> 16) & 1u)) >> 16;  // RNE
  return (u16)r;
}

__device__ __forceinline__ u32 pack2bf(float a, float b) {
  return (u32)f2bf(a) | ((u32)f2bf(b) << 16);
}

__device__ __forceinline__ void gload_lds16(const u16* g, u16* l) {
  __builtin_amdgcn_global_load_lds(
      (const __attribute__((address_space(1))) u32*)(g),
      (__attribute__((address_space(3))) u32*)(l), 16, 0, 0);
}

// ---------------- GroupNorm statistics: one block per (b, group) ----------------
__global__ __launch_bounds__(256) void gn_stats_kernel(const float* __restrict__ x,
                                                       float* __restrict__ stats) {
  const int bg = blockIdx.x;
  const float4* xp = (const float4*)(x + (size_t)bg * 16 * NN);
  const int n4 = 16 * NN / 4;
  float s = 0.f, ss = 0.f;
  for (int i = threadIdx.x; i < n4; i += 256) {
    float4 v = xp[i];
    s += v.x + v.y + v.z + v.w;
    ss += v.x * v.x + v.y * v.y + v.z * v.z + v.w * v.w;
  }
  for (int off = 32; off > 0; off >>= 1) {
    s += __shfl_down(s, off, 64);
    ss += __shfl_down(ss, off, 64);
  }
  __shared__ float rs[4], rss[4];
  const int wid = threadIdx.x >> 6, lane = threadIdx.x & 63;
  if (lane == 0) { rs[wid] = s; rss[wid] = ss; }
  __syncthreads();
  if (threadIdx.x == 0) {
    float S = rs[0] + rs[1] + rs[2] + rs[3];
    float SS = rss[0] + rss[1] + rss[2] + rss[3];
    const float invn = 1.0f / (16.0f * NN);
    float mean = S * invn;
    float var = SS * invn - mean * mean;
    stats[bg * 2] = mean;
    stats[bg * 2 + 1] = rsqrtf(var + EPSV);
  }
}

// ------------- GN-apply + transpose: x [C][N] fp32 -> hT [N][C] bf16 -------------
__global__ __launch_bounds__(256) void gn_transpose_kernel(
    const float* __restrict__ x, const float* __restrict__ gamma,
    const float* __restrict__ beta, const float* __restrict__ stats,
    u16* __restrict__ hT) {
  __shared__ __align__(16) u16 Ts[64 * 64];  // XOR-swizzled 16B units
  const int b = blockIdx.z;
  const int c0 = blockIdx.y * 64;
  const int n0 = blockIdx.x * 64;
  const int t = threadIdx.x;
  const float* xb = x + ((size_t)b * CC + c0) * NN;
#pragma unroll
  for (int it = 0; it < 2; ++it) {
    const int U = it * 256 + t;
    const int r = U >> 3, cu = U & 7;  // r = channel row, cu = 8-elem n unit
    const int c = c0 + r;
    const int g = c >> 4;
    const float mean = stats[(b * GG + g) * 2];
    const float rstd = stats[(b * GG + g) * 2 + 1];
    const float aa = rstd * gamma[c];
    const float dd = beta[c] - mean * aa;
    const float* src = xb + (size_t)r * NN + n0 + cu * 8;
    float4 v0 = *(const float4*)src;
    float4 v1 = *(const float4*)(src + 4);
    uint4 pk;
    pk.x = pack2bf(fmaf(aa, v0.x, dd), fmaf(aa, v0.y, dd));
    pk.y = pack2bf(fmaf(aa, v0.z, dd), fmaf(aa, v0.w, dd));
    pk.z = pack2bf(fmaf(aa, v1.x, dd), fmaf(aa, v1.y, dd));
    pk.w = pack2bf(fmaf(aa, v1.z, dd), fmaf(aa, v1.w, dd));
    const int pu = cu ^ ((r >> 3) & 7);
    *(uint4*)((char*)Ts + r * 128 + pu * 16) = pk;
  }
  __syncthreads();
#pragma unroll
  for (int it = 0; it < 2; ++it) {
    const int U = it * 256 + t;
    const int n = U >> 3, cu2 = U & 7;
    bf16x8 v;
#pragma unroll
    for (int jj = 0; jj < 8; ++jj) {
      const int c = cu2 * 8 + jj;
      v[jj] = (short)Ts[c * 64 + (((n >> 3) ^ cu2) << 3) + (n & 7)];
    }
    *(bf16x8*)(hT + ((size_t)b * NN + n0 + n) * CC + c0 + cu2 * 8) = v;
  }
}

// ------------- w_qkv fp32 -> bf16 (one-shot, tiny) -------------
__global__ __launch_bounds__(256) void convert_w_kernel(const float* __restrict__ w,
                                                        u16* __restrict__ wb, int n8) {
  const int i = blockIdx.x * 256 + threadIdx.x;
  if (i >= n8) return;
  const float4 a = *(const float4*)(w + (size_t)i * 8);
  const float4 b = *(const float4*)(w + (size_t)i * 8 + 4);
  uint4 pk;
  pk.x = pack2bf(a.x, a.y);
  pk.y = pack2bf(a.z, a.w);
  pk.z = pack2bf(b.x, b.y);
  pk.w = pack2bf(b.z, b.w);
  *(uint4*)(wb + (size_t)i * 8) = pk;
}

// ------------- QKV GEMM on MFMA: qkv[o][n] = wbf[o][c] * hT[n][c]^T + bias -------------
__global__ __launch_bounds__(256) void qkv_mfma_kernel(
    const u16* __restrict__ hT, const u16* __restrict__ wbf,
    const float* __restrict__ bqkv, u16* __restrict__ qkv) {
  __shared__ __align__(16) u16 Asb[128 * 32 * 2];  // A tile | B tile, 16 KB
  u16* const Bsb = Asb + 128 * 32;
  const int b = blockIdx.z;
  const int o0 = blockIdx.y * 128;
  const int n0 = blockIdx.x * 128;
  const int t = threadIdx.x;
  const int w = t >> 6;
  const int lane = t & 63;
  const int quad = lane >> 4;
  const int m16 = lane & 15;
  const int wm = w >> 1, wn = w & 1;

  const int sr = lane >> 2;
  const int gu = (lane & 3) ^ ((lane >> 3) & 3);
  const u16* gA0 = wbf + (size_t)(o0 + w * 32 + sr) * CC + gu * 8;
  const u16* gA1 = gA0 + (size_t)16 * CC;
  const u16* hTb = hT + (size_t)b * NN * CC;
  const u16* gB0 = hTb + (size_t)(n0 + w * 32 + sr) * CC + gu * 8;
  const u16* gB1 = gB0 + (size_t)16 * CC;
  u16* const lA0 = Asb + (w * 32) * 32;
  u16* const lA1 = Asb + (w * 32 + 16) * 32;
  u16* const lB0 = Bsb + (w * 32) * 32;
  u16* const lB1 = Bsb + (w * 32 + 16) * 32;

  const int sfr = (m16 >> 1) & 3;
  const u16* aP[4];
  const u16* bP[4];
#pragma unroll
  for (int mt = 0; mt < 4; ++mt)
    aP[mt] = Asb + (wm * 64 + mt * 16 + m16) * 32 + (quad ^ sfr) * 8;
#pragma unroll
  for (int ct = 0; ct < 4; ++ct)
    bP[ct] = Bsb + (wn * 64 + ct * 16 + m16) * 32 + (quad ^ sfr) * 8;

  f32x4 acc[4][4];
#pragma unroll
  for (int mt = 0; mt < 4; ++mt)
#pragma unroll
    for (int ct = 0; ct < 4; ++ct) acc[mt][ct] = (f32x4){0.f, 0.f, 0.f, 0.f};

  for (int kk = 0; kk < 16; ++kk) {
    __syncthreads();
    gload_lds16(gA0, lA0);
    gload_lds16(gA1, lA1);
    gload_lds16(gB0, lB0);
    gload_lds16(gB1, lB1);
    gA0 += 32; gA1 += 32; gB0 += 32; gB1 += 32;
    __syncthreads();
    bf16x8 af[4], bfr[4];
#pragma unroll
    for (int mt = 0; mt < 4; ++mt) af[mt] = *(const bf16x8*)aP[mt];
#pragma unroll
    for (int ct = 0; ct < 4; ++ct) bfr[ct] = *(const bf16x8*)bP[ct];
#pragma unroll
    for (int mt = 0; mt < 4; ++mt)
#pragma unroll
      for (int ct = 0; ct < 4; ++ct)
        acc[mt][ct] = __builtin_amdgcn_mfma_f32_16x16x32_bf16(af[mt], bfr[ct],
                                                              acc[mt][ct], 0, 0, 0);
  }
  __syncthreads();

  u16* qb = qkv + (size_t)b * BATCH_STRIDE;
  size_t roff;
  int lo0;
  if (o0 < 512) { roff = Q_OFF; lo0 = o0; }
  else if (o0 < 1024) { roff = K_OFF; lo0 = o0 - 512; }
  else { roff = V_OFF; lo0 = o0 - 1024; }

  u16* const scr = Asb + w * 1024;
#pragma unroll
  for (int mt = 0; mt < 4; ++mt) {
#pragma unroll
    for (int ct = 0; ct < 4; ++ct) {
#pragma unroll
      for (int i = 0; i < 4; ++i) {
        const int row = quad * 4 + i;
        const int nn = ct * 16 + m16;
        const int pu = (nn >> 3) ^ ((row & 7) ^ (row >> 3));
        scr[row * 64 + pu * 8 + (nn & 7)] =
            f2bf(acc[mt][ct][i] + bqkv[o0 + wm * 64 + mt * 16 + row]);
      }
    }
    __syncthreads();
#pragma unroll
    for (int half = 0; half < 2; ++half) {
      const int idx = half * 64 + lane;
      const int row = idx >> 3;
      const int cu = idx & 7;
      const int pu = cu ^ ((row & 7) ^ (row >> 3));
      bf16x8 vv = *(const bf16x8*)(scr + row * 64 + pu * 8);
      *(bf16x8*)(qb + roff + (size_t)(lo0 + wm * 64 + mt * 16 + row) * NN +
                 n0 + wn * 64 + cu * 8) = vv;
    }
    __syncthreads();
  }
}

// ------------- 64x64 tile transpose q,k: [c][n] -> [n][c] bf16 -------------
__global__ __launch_bounds__(256) void transpose_qk_kernel(
    const u16* __restrict__ qkvbuf, u16* __restrict__ qT, u16* __restrict__ kT) {
  __shared__ __align__(16) u16 Ts[64 * 64];  // XOR-swizzled 16B units
  const int b = blockIdx.z >> 1;
  const int which = blockIdx.z & 1;
  const int c0 = blockIdx.y * 64;
  const int n0 = blockIdx.x * 64;
  const int t = threadIdx.x;
  const u16* src = qkvbuf + (size_t)b * BATCH_STRIDE + (which ? K_OFF : Q_OFF);
  u16* dst = (which ? kT : qT) + (size_t)b * (CC * NN);
#pragma unroll
  for (int it = 0; it < 2; ++it) {
    const int U = it * 256 + t;
    const int r = U >> 3, cu = U & 7;
    const int pu = cu ^ ((r >> 3) & 7);
    *(uint4*)((char*)Ts + r * 128 + pu * 16) =
        *(const uint4*)(src + (size_t)(c0 + r) * NN + n0 + cu * 8);
  }
  __syncthreads();
#pragma unroll
  for (int it = 0; it < 2; ++it) {
    const int U = it * 256 + t;
    const int n = U >> 3, cu2 = U & 7;
    bf16x8 v;
#pragma unroll
    for (int jj = 0; jj < 8; ++jj) {
      const int c = cu2 * 8 + jj;
      v[jj] = (short)Ts[c * 64 + (((n >> 3) ^ cu2) << 3) + (n & 7)];
    }
    *(bf16x8*)(dst + (size_t)(n0 + n) * CC + c0 + cu2 * 8) = v;
  }
}

// ------------- Flash attention v9: BQ=64, split-S + pair exchange, no dup ----
// 8 waves; wave (wq=w>>1, wc=w&1): 16 q-rows x 256 channels. Register budget is
// hard-capped ~104 by the toolchain (R2-R8): demand kept ~100 by (a) oacc = 16
// f32x4, (b) Q in LDS, (c) K dbuf via global_load_lds (no staging regs),
// (d) V read directly from global (R1-verified B-frag pattern; L2/L3-resident).
// S duplication removed: each wave computes its 16-key half (16 MFMA) and the
// wave pair exchanges raw S tiles via 8KB LDS; post-exchange register state is
// bit-identical to R8's (s0,s1), so softmax/PV/epilogue are unchanged.
__global__ __launch_bounds__(512, 1) void attn_mfma_kernel(
    u16* __restrict__ qkvbuf, const u16* __restrict__ qT, const u16* __restrict__ kT) {
  // Qs 64K | KtA 32K | KtB 32K | P 10K | Sx 8K = 146 KB
  __shared__ __align__(16) u16 smem[74752];
  u16* const Qs = smem;              // [64 q][512 c], row-XOR swizzled units
  u16* const KtA = smem + 32768;     // [32 k][512 c]
  u16* const KtB = smem + 49152;
  u16* const Pbase = smem + 65536;   // 8 x [16][40] u16
  float* const Sx = (float*)(smem + 70656);  // 8 x [16 q][16 k] f32

  // XCD-aware: HW linear id % 8 -> bind batch to XCD.
  const int flat = blockIdx.y * 64 + blockIdx.x;   // grid = (64, 8)
  const int b = flat & 7;
  const int i0 = (flat >> 3) * 64;
  const int t = threadIdx.x;
  const int w = t >> 6;
  const int lane = t & 63;
  const int quad = lane >> 4;
  const int m16 = lane & 15;
  const int wq = w >> 1;   // q-tile 0..3
  const int wc = w & 1;    // key-half for S, channel-half for PV

  const u16* vb = qkvbuf + (size_t)b * BATCH_STRIDE + V_OFF;
  float* obuf = (float*)(qkvbuf + (size_t)b * BATCH_STRIDE + Q_OFF);  // aliases q+k
  const u16* qTb = qT + (size_t)b * (CC * NN);
  const u16* kTb = kT + (size_t)b * (CC * NN);
  u16* const myP = Pbase + w * 640;          // [16][40] wave-private
  float* const mySx = Sx + w * 256;          // [16][16]
  const float* const otSx = Sx + (w ^ 1) * 256;

  // ---- prologue: stage Q (once) + K tile 0, all via global_load_lds ----
#pragma unroll
  for (int it = 0; it < 8; ++it) {
    const int r = it * 8 + w;
    gload_lds16(qTb + (size_t)(i0 + r) * CC + (lane ^ (r & 7)) * 8,
                Qs + r * 512 + lane * 8);
  }
#pragma unroll
  for (int it = 0; it < 4; ++it) {
    const int j = it * 8 + w;
    gload_lds16(kTb + (size_t)j * CC + (lane ^ (j & 7)) * 8, KtA + j * 512 + lane * 8);
  }

  float m_r = -1e30f, l_r = 0.f;  // per q-row (q=m16), replicated across quads
#define ODECL(ct) f32x4 o##ct = (f32x4){0.f, 0.f, 0.f, 0.f};
  FOR16(ODECL)
#undef ODECL

  __syncthreads();  // Q + K tile 0 staged (vmcnt drained)

  const u16* const Qrow = Qs + (wq * 16 + m16) * 512;
  const int sz = m16 & 7;
  const int krow = wc * 16 + m16;            // this wave's key row in the tile
  // V direct-global base: c = wc*256 + ct*16 + m16, k-offset quad*8 within tile
  const u16* const vrow_g = vb + (size_t)(wc * 256 + m16) * NN + quad * 8;

  for (int jt = 0; jt < NN / 32; ++jt) {
    const u16* Ktc = (jt & 1) ? KtB : KtA;
    u16* Ktn = (jt & 1) ? KtA : KtB;
    // ---- issue next K tile (global_load_lds; drains at next barrier) ----
    if (jt + 1 < NN / 32) {
      const int j0n = (jt + 1) * 32;
#pragma unroll
      for (int it = 0; it < 4; ++it) {
        const int j = it * 8 + w;
        gload_lds16(kTb + (size_t)(j0n + j) * CC + (lane ^ (j & 7)) * 8,
                    Ktn + j * 512 + lane * 8);
      }
    }
    // ---- S half-tile: 16 MFMA over K=512 ----
    f32x4 sh = (f32x4){0.f, 0.f, 0.f, 0.f};
    {
      const u16* kh = Ktc + krow * 512;
#define SSTEP(kc) { const int u = ((kc * 4 + quad) ^ sz) * 8; \
      bf16x8 qf = *(const bf16x8*)(Qrow + u); \
      bf16x8 ka = *(const bf16x8*)(kh + u); \
      sh = __builtin_amdgcn_mfma_f32_16x16x32_bf16(ka, qf, sh, 0, 0, 0); }
      FOR16(SSTEP)
#undef SSTEP
    }
    // ---- pair exchange of raw S tiles ----
    *(f32x4*)(mySx + m16 * 16 + quad * 4) = sh;
    __syncthreads();  // Sx visible (also drains K prefetch vmcnt)
    f32x4 so = *(const f32x4*)(otSx + m16 * 16 + quad * 4);
    f32x4 s0 = wc ? so : sh;
    f32x4 s1 = wc ? sh : so;
    // ---- wave-local online softmax (identical to R8) ----
    float p0 = s0[0] * SCALE, p1 = s0[1] * SCALE, p2 = s0[2] * SCALE, p3 = s0[3] * SCALE;
    float p4 = s1[0] * SCALE, p5 = s1[1] * SCALE, p6 = s1[2] * SCALE, p7 = s1[3] * SCALE;
    float mx = fmaxf(fmaxf(fmaxf(p0, p1), fmaxf(p2, p3)),
                     fmaxf(fmaxf(p4, p5), fmaxf(p6, p7)));
    mx = fmaxf(mx, __shfl_xor(mx, 16));
    mx = fmaxf(mx, __shfl_xor(mx, 32));
    const float mold = m_r;
    const float mnew = fmaxf(mold, mx);
    m_r = mnew;
    const float alpha = __expf(mold - mnew);
    p0 = __expf(p0 - mnew); p1 = __expf(p1 - mnew);
    p2 = __expf(p2 - mnew); p3 = __expf(p3 - mnew);
    p4 = __expf(p4 - mnew); p5 = __expf(p5 - mnew);
    p6 = __expf(p6 - mnew); p7 = __expf(p7 - mnew);
    float sum = ((p0 + p1) + (p2 + p3)) + ((p4 + p5) + (p6 + p7));
    sum += __shfl_xor(sum, 16);
    sum += __shfl_xor(sum, 32);
    l_r = l_r * alpha + sum;
    uint2 pw0, pw1;
    pw0.x = pack2bf(p0, p1); pw0.y = pack2bf(p2, p3);
    pw1.x = pack2bf(p4, p5); pw1.y = pack2bf(p6, p7);
    *(uint2*)(myP + m16 * 40 + quad * 4) = pw0;
    *(uint2*)(myP + m16 * 40 + 16 + quad * 4) = pw1;
    asm volatile("s_waitcnt lgkmcnt(0)" ::: "memory");
    bf16x8 pf = *(const bf16x8*)(myP + m16 * 40 + quad * 8);
    const float a0 = __shfl(alpha, quad * 4 + 0);
    const float a1 = __shfl(alpha, quad * 4 + 1);
    const float a2 = __shfl(alpha, quad * 4 + 2);
    const float a3 = __shfl(alpha, quad * 4 + 3);
    // ---- PV: V B-frags direct from global (R1 pattern), 16 MFMA ----
    const u16* vg = vrow_g + jt * 32;
    const bool nores = __all(mnew == mold);
#define PVN(ct) { bf16x8 vf = *(const bf16x8*)(vg + (size_t)(ct * 16) * NN); \
      o##ct = __builtin_amdgcn_mfma_f32_16x16x32_bf16(pf, vf, o##ct, 0, 0, 0); }
#define PVR(ct) { bf16x8 vf = *(const bf16x8*)(vg + (size_t)(ct * 16) * NN); \
      f32x4 oo = o##ct; oo[0] *= a0; oo[1] *= a1; oo[2] *= a2; oo[3] *= a3; \
      o##ct = __builtin_amdgcn_mfma_f32_16x16x32_bf16(pf, vf, oo, 0, 0, 0); }
    if (nores) {
      FOR16(PVN)
    } else {
      FOR16(PVR)
    }
#undef PVN
#undef PVR
    __syncthreads();  // all waves done with Ktc + Sx; next K tile visible
  }
  // ---- epilogue: direct stores (identical to R8) ----
  const float invl = 1.0f / l_r;
  const float il0 = __shfl(invl, quad * 4 + 0);
  const float il1 = __shfl(invl, quad * 4 + 1);
  const float il2 = __shfl(invl, quad * 4 + 2);
  const float il3 = __shfl(invl, quad * 4 + 3);
  const size_t ncol = i0 + wq * 16 + quad * 4;
#define EPI(ct) { float4 ov; \
      ov.x = o##ct[0] * il0; ov.y = o##ct[1] * il1; \
      ov.z = o##ct[2] * il2; ov.w = o##ct[3] * il3; \
      *(float4*)(obuf + (size_t)(wc * 256 + ct * 16 + m16) * NN + ncol) = ov; }
  FOR16(EPI)
#undef EPI
}

// ------------- output projection + bias + residual (obuf aliased in qkv ws) -------------
__global__ __launch_bounds__(256) void proj_kernel(
    const u16* __restrict__ qkvbuf, const float* __restrict__ wout,
    const float* __restrict__ bout, const float* __restrict__ x,
    float* __restrict__ out) {
  __shared__ __align__(16) float Wt[16][68];
  __shared__ __align__(16) float Ht[16][68];
  const int b = blockIdx.z;
  const int o0 = blockIdx.y * 64;
  const int n0 = blockIdx.x * 64;
  const int t = threadIdx.x;
  const int to = (t >> 4) * 4;
  const int tn = (t & 15) * 4;
  const int wo = t >> 2;
  const int wk = (t & 3) * 4;
  const int xc = t >> 4;
  const int xn = (t & 15) * 4;
  const float* ob = (const float*)(qkvbuf + (size_t)b * BATCH_STRIDE + Q_OFF);
  float acc[4][4] = {{0.f}};
  for (int kk = 0; kk < CC; kk += 16) {
    float4 wv = *(const float4*)(wout + (size_t)(o0 + wo) * CC + kk + wk);
    float4 hv = *(const float4*)(ob + (size_t)(kk + xc) * NN + n0 + xn);
    __syncthreads();
    Wt[wk + 0][wo] = wv.x;
    Wt[wk + 1][wo] = wv.y;
    Wt[wk + 2][wo] = wv.z;
    Wt[wk + 3][wo] = wv.w;
    *(float4*)&Ht[xc][xn] = hv;
    __syncthreads();
#pragma unroll
    for (int k = 0; k < 16; ++k) {
      float4 w4 = *(const float4*)&Wt[k][to];
      float4 h4 = *(const float4*)&Ht[k][tn];
      acc[0][0] = fmaf(w4.x, h4.x, acc[0][0]);
      acc[0][1] = fmaf(w4.x, h4.y, acc[0][1]);
      acc[0][2] = fmaf(w4.x, h4.z, acc[0][2]);
      acc[0][3] = fmaf(w4.x, h4.w, acc[0][3]);
      acc[1][0] = fmaf(w4.y, h4.x, acc[1][0]);
      acc[1][1] = fmaf(w4.y, h4.y, acc[1][1]);
      acc[1][2] = fmaf(w4.y, h4.z, acc[1][2]);
      acc[1][3] = fmaf(w4.y, h4.w, acc[1][3]);
      acc[2][0] = fmaf(w4.z, h4.x, acc[2][0]);
      acc[2][1] = fmaf(w4.z, h4.y, acc[2][1]);
      acc[2][2] = fmaf(w4.z, h4.z, acc[2][2]);
      acc[2][3] = fmaf(w4.z, h4.w, acc[2][3]);
      acc[3][0] = fmaf(w4.w, h4.x, acc[3][0]);
      acc[3][1] = fmaf(w4.w, h4.y, acc[3][1]);
      acc[3][2] = fmaf(w4.w, h4.z, acc[3][2]);
      acc[3][3] = fmaf(w4.w, h4.w, acc[3][3]);
    }
  }
#pragma unroll
  for (int i = 0; i < 4; ++i) {
    const int o = o0 + to + i;
    const float bias = bout[o];
    const size_t idx = ((size_t)b * CC + o) * NN + n0 + tn;
    float4 xv = *(const float4*)(x + idx);
    float4 r;
    r.x = acc[i][0] + bias + xv.x;
    r.y = acc[i][1] + bias + xv.y;
    r.z = acc[i][2] + bias + xv.z;
    r.w = acc[i][3] + bias + xv.w;
    *(float4*)(out + idx) = r;
  }
}

extern "C" void kernel_launch(void* const* d_in, const int* in_sizes, int n_in,
                              void* d_out, int out_size, void* d_ws, size_t ws_size,
                              hipStream_t stream) {
  const float* x = (const float*)d_in[0];
  const float* gamma = (const float*)d_in[1];
  const float* beta = (const float*)d_in[2];
  const float* wqkv = (const float*)d_in[3];
  const float* bqkv = (const float*)d_in[4];
  const float* wout = (const float*)d_in[5];
  const float* bout = (const float*)d_in[6];
  float* out = (float*)d_out;

  char* ws = (char*)d_ws;
  float* stats = (float*)ws;                           // 2 KB
  u16* qkv = (u16*)(ws + 4096);                        // bf16 [v|q|k] per batch
  u16* qT = (u16*)(ws + 4096 + (size_t)BB * OQKV * NN * 2);      // 33.55 MB
  u16* kT = qT + (size_t)BB * CC * NN;                            // 33.55 MB
  u16* hT = qT;    // alias: [B][N][C] bf16, consumed before transpose_qk writes qT
  u16* wbf = kT;   // alias: [1536][512] bf16

  gn_stats_kernel<<<BB * GG, 256, 0, stream>>>(x, stats);
  gn_transpose_kernel<<<dim3(NN / 64, CC / 64, BB), 256, 0, stream>>>(
      x, gamma, beta, stats, hT);
  convert_w_kernel<<<(OQKV * CC / 8 + 255) / 256, 256, 0, stream>>>(
      wqkv, wbf, OQKV * CC / 8);
  qkv_mfma_kernel<<<dim3(NN / 128, OQKV / 128, BB), 256, 0, stream>>>(
      hT, wbf, bqkv, qkv);
  transpose_qk_kernel<<<dim3(NN / 64, CC / 64, BB * 2), 256, 0, stream>>>(qkv, qT, kT);
  attn_mfma_kernel<<<dim3(NN / 64, BB), 512, 0, stream>>>(qkv, qT, kT);
  proj_kernel<<<dim3(NN / 64, CC / 64, BB), 256, 0, stream>>>(qkv, wout, bout, x, out);
}